// Round 1
// baseline (1618.796 us; speedup 1.0000x reference)
//
#include <hip/hip_runtime.h>
#include <math.h>

#define NTOK 4096
#define DMODEL 256
#define G_GENES 2000

// ---------------- helpers ----------------
__device__ __forceinline__ float gelu_exact(float x) {
    return 0.5f * x * (1.0f + erff(x * 0.70710678118654752f));
}
__device__ __forceinline__ float softplus_f(float x) {
    return fmaxf(x, 0.0f) + log1pf(expf(-fabsf(x)));
}

// ---------------- fourier encoding ----------------
// F[n, 0:64] = sin(2pi * pos[n] @ B[:,m]),  F[n, 64:128] = cos(...)
__global__ __launch_bounds__(64) void fourier_k(const float* __restrict__ pos,
                                                const float* __restrict__ B,
                                                float* __restrict__ F) {
    int n = blockIdx.x, m = threadIdx.x;
    float xp = 6.283185307179586f *
               (pos[n * 3 + 0] * B[m] + pos[n * 3 + 1] * B[64 + m] + pos[n * 3 + 2] * B[128 + m]);
    F[(size_t)n * 128 + m]      = sinf(xp);
    F[(size_t)n * 128 + 64 + m] = cosf(xp);
}

// ---------------- generic tiled fp32 GEMM ----------------
// C[M,Ncols] (+)= epi(A[M,K] @ W[K,Ncols] + bias)
// 64x64 tile, BK=16, 256 threads, 4x4 per thread. K and lda,ldw multiples of 4;
// K range handled must be a multiple of 16 (true for all uses here).
#define EPI_PLAIN 0
#define EPI_ACC 1
#define EPI_GELU 2
#define EPI_ROWSCALE_ACC 3
#define EPI_ATOMIC 4
#define EPI_GENE 5

template <int EPI>
__global__ __launch_bounds__(256) void gemm_k(
    const float* __restrict__ A, const float* __restrict__ W,
    const float* __restrict__ bias, float* __restrict__ C,
    int M, int K, int Ncols, int lda, int ldw, int ldc,
    const float* __restrict__ rowscale, int rsStride,
    float* __restrict__ outMu, float* __restrict__ outTheta, int kChunk) {
    __shared__ float As[64][17];
    __shared__ float Ws[16][64];
    const int m0 = blockIdx.x * 64;
    const int n0 = blockIdx.y * 64;
    const int tid = threadIdx.x;
    const int tx = tid & 15, ty = tid >> 4;
    const int k_begin = blockIdx.z * kChunk;
    const int k_end = (k_begin + kChunk < K) ? (k_begin + kChunk) : K;

    const int la_m = tid >> 2;        // 0..63
    const int la_k = (tid & 3) * 4;   // 0,4,8,12
    const int lw_r = tid >> 4;        // 0..15
    const int lw_c = (tid & 15) * 4;  // 0..60
    const bool fullN = (n0 + 64 <= Ncols);

    float acc[4][4] = {};

    for (int k0 = k_begin; k0 < k_end; k0 += 16) {
        float4 av = *(const float4*)(A + (size_t)(m0 + la_m) * lda + k0 + la_k);
        As[la_m][la_k + 0] = av.x; As[la_m][la_k + 1] = av.y;
        As[la_m][la_k + 2] = av.z; As[la_m][la_k + 3] = av.w;
        int gr = k0 + lw_r;
        if (fullN) {
            float4 wv = *(const float4*)(W + (size_t)gr * ldw + n0 + lw_c);
            Ws[lw_r][lw_c + 0] = wv.x; Ws[lw_r][lw_c + 1] = wv.y;
            Ws[lw_r][lw_c + 2] = wv.z; Ws[lw_r][lw_c + 3] = wv.w;
        } else {
#pragma unroll
            for (int j = 0; j < 4; j++) {
                int gc = n0 + lw_c + j;
                Ws[lw_r][lw_c + j] = (gc < Ncols) ? W[(size_t)gr * ldw + gc] : 0.0f;
            }
        }
        __syncthreads();
#pragma unroll
        for (int kk = 0; kk < 16; kk++) {
            float a[4], b[4];
#pragma unroll
            for (int i = 0; i < 4; i++) a[i] = As[ty * 4 + i][kk];
#pragma unroll
            for (int j = 0; j < 4; j++) b[j] = Ws[kk][tx * 4 + j];
#pragma unroll
            for (int i = 0; i < 4; i++)
#pragma unroll
                for (int j = 0; j < 4; j++) acc[i][j] = fmaf(a[i], b[j], acc[i][j]);
        }
        __syncthreads();
    }

#pragma unroll
    for (int i = 0; i < 4; i++) {
        int m = m0 + ty * 4 + i;
#pragma unroll
        for (int j = 0; j < 4; j++) {
            int c = n0 + tx * 4 + j;
            if (c >= Ncols) continue;
            float v = acc[i][j];
            if (EPI != EPI_ATOMIC) {
                if (bias) v += bias[c];
            }
            size_t idx = (size_t)m * ldc + c;
            if (EPI == EPI_PLAIN) {
                C[idx] = v;
            } else if (EPI == EPI_ACC) {
                C[idx] += v;
            } else if (EPI == EPI_GELU) {
                C[idx] = gelu_exact(v);
            } else if (EPI == EPI_ROWSCALE_ACC) {
                C[idx] += rowscale[(size_t)m * rsStride] * v;
            } else if (EPI == EPI_ATOMIC) {
                atomicAdd(&C[idx], v);
            } else if (EPI == EPI_GENE) {
                float sp = softplus_f(v);
                size_t gi = (size_t)m * G_GENES + (c >> 1);
                if ((c & 1) == 0) outMu[gi] = sp;
                else outTheta[gi] = sp + 1e-6f;
            }
        }
    }
}

// ---------------- attention: scores = Q_h @ K_h^T / 8 ----------------
__global__ __launch_bounds__(256) void scores_k(const float* __restrict__ Q,
                                                const float* __restrict__ Km,
                                                float* __restrict__ S, int head) {
    __shared__ float Qs[64][65];
    __shared__ float Ks[64][65];
    int m0 = blockIdx.x * 64, n0 = blockIdx.y * 64;
    int tid = threadIdx.x, tx = tid & 15, ty = tid >> 4;
    int row = tid >> 2, c0 = (tid & 3) * 16;
    const float* qp = Q + (size_t)(m0 + row) * DMODEL + head * 64 + c0;
    const float* kp = Km + (size_t)(n0 + row) * DMODEL + head * 64 + c0;
#pragma unroll
    for (int i = 0; i < 16; i += 4) {
        float4 qv = *(const float4*)(qp + i);
        Qs[row][c0 + i + 0] = qv.x; Qs[row][c0 + i + 1] = qv.y;
        Qs[row][c0 + i + 2] = qv.z; Qs[row][c0 + i + 3] = qv.w;
        float4 kv = *(const float4*)(kp + i);
        Ks[row][c0 + i + 0] = kv.x; Ks[row][c0 + i + 1] = kv.y;
        Ks[row][c0 + i + 2] = kv.z; Ks[row][c0 + i + 3] = kv.w;
    }
    __syncthreads();
    float acc[4][4] = {};
#pragma unroll 8
    for (int k = 0; k < 64; k++) {
        float a[4], b[4];
#pragma unroll
        for (int i = 0; i < 4; i++) a[i] = Qs[ty * 4 + i][k];
#pragma unroll
        for (int j = 0; j < 4; j++) b[j] = Ks[tx * 4 + j][k];
#pragma unroll
        for (int i = 0; i < 4; i++)
#pragma unroll
            for (int j = 0; j < 4; j++) acc[i][j] = fmaf(a[i], b[j], acc[i][j]);
    }
#pragma unroll
    for (int i = 0; i < 4; i++)
#pragma unroll
        for (int j = 0; j < 4; j++)
            S[(size_t)(m0 + ty * 4 + i) * NTOK + n0 + tx * 4 + j] = acc[i][j] * 0.125f;
}

// ---------------- row softmax over 4096 cols ----------------
__global__ __launch_bounds__(256) void softmax_k(float* __restrict__ S) {
    __shared__ float sm[4];
    size_t base = (size_t)blockIdx.x * NTOK;
    int t = threadIdx.x;
    float v[16];
    float mx = -3.4e38f;
#pragma unroll
    for (int i = 0; i < 16; i++) {
        v[i] = S[base + t + (size_t)i * 256];
        mx = fmaxf(mx, v[i]);
    }
    for (int off = 32; off; off >>= 1) mx = fmaxf(mx, __shfl_down(mx, off));
    if ((t & 63) == 0) sm[t >> 6] = mx;
    __syncthreads();
    mx = fmaxf(fmaxf(sm[0], sm[1]), fmaxf(sm[2], sm[3]));
    float s = 0.0f;
#pragma unroll
    for (int i = 0; i < 16; i++) {
        v[i] = __expf(v[i] - mx);
        s += v[i];
    }
    for (int off = 32; off; off >>= 1) s += __shfl_down(s, off);
    __syncthreads();
    if ((t & 63) == 0) sm[t >> 6] = s;
    __syncthreads();
    s = sm[0] + sm[1] + sm[2] + sm[3];
    float inv = 1.0f / s;
#pragma unroll
    for (int i = 0; i < 16; i++) S[base + t + (size_t)i * 256] = v[i] * inv;
}

// ---------------- layernorm (+optional residual input, +optional gelu out) ----------------
__global__ __launch_bounds__(256) void ln_k(const float* __restrict__ X,
                                            const float* __restrict__ R,
                                            const float* __restrict__ gam,
                                            const float* __restrict__ bet,
                                            float* __restrict__ O, int doGelu) {
    __shared__ float sm[4];
    int n = blockIdx.x, c = threadIdx.x;
    float x = X[(size_t)n * DMODEL + c];
    if (R) x += R[(size_t)n * DMODEL + c];
    float s = x;
    for (int off = 32; off; off >>= 1) s += __shfl_down(s, off);
    if ((c & 63) == 0) sm[c >> 6] = s;
    __syncthreads();
    float mean = (sm[0] + sm[1] + sm[2] + sm[3]) * (1.0f / DMODEL);
    float d = x - mean;
    float s2 = d * d;
    for (int off = 32; off; off >>= 1) s2 += __shfl_down(s2, off);
    __syncthreads();
    if ((c & 63) == 0) sm[c >> 6] = s2;
    __syncthreads();
    float var = (sm[0] + sm[1] + sm[2] + sm[3]) * (1.0f / DMODEL);
    float y = d * rsqrtf(var + 1e-5f) * gam[c] + bet[c];
    if (doGelu) y = gelu_exact(y);
    O[(size_t)n * DMODEL + c] = y;
}

// ---------------- router: top-1 gate ----------------
__global__ __launch_bounds__(64) void router_k(const float* __restrict__ z2,
                                               const float* __restrict__ grad,
                                               const float* __restrict__ Wr,
                                               const float* __restrict__ br,
                                               float* __restrict__ gate) {
    int n = blockIdx.x, t = threadIdx.x;
    float p0 = 0, p1 = 0, p2 = 0, p3 = 0;
#pragma unroll
    for (int i = 0; i < 4; i++) {
        int d = t + i * 64;
        float zv = z2[(size_t)n * DMODEL + d];
        p0 = fmaf(zv, Wr[d * 4 + 0], p0);
        p1 = fmaf(zv, Wr[d * 4 + 1], p1);
        p2 = fmaf(zv, Wr[d * 4 + 2], p2);
        p3 = fmaf(zv, Wr[d * 4 + 3], p3);
    }
    for (int off = 32; off; off >>= 1) {
        p0 += __shfl_down(p0, off);
        p1 += __shfl_down(p1, off);
        p2 += __shfl_down(p2, off);
        p3 += __shfl_down(p3, off);
    }
    if (t == 0) {
        float gv = grad[n];
        float l[4];
        l[0] = p0 + gv * Wr[256 * 4 + 0] + br[0];
        l[1] = p1 + gv * Wr[256 * 4 + 1] + br[1];
        l[2] = p2 + gv * Wr[256 * 4 + 2] + br[2];
        l[3] = p3 + gv * Wr[256 * 4 + 3] + br[3];
        float mx = fmaxf(fmaxf(l[0], l[1]), fmaxf(l[2], l[3]));
        float e[4], s = 0;
#pragma unroll
        for (int i = 0; i < 4; i++) { e[i] = __expf(l[i] - mx); s += e[i]; }
        int am = 0;
        float best = l[0];
#pragma unroll
        for (int i = 1; i < 4; i++)
            if (l[i] > best) { best = l[i]; am = i; }
        float p = e[am] / s;
#pragma unroll
        for (int i = 0; i < 4; i++) gate[(size_t)n * 4 + i] = (i == am) ? p : 0.0f;
    }
}

// ---------------- functional head final: g = sigmoid(f @ Wf2 + bf2) ----------------
__global__ __launch_bounds__(256) void ghead_k(const float* __restrict__ f,
                                               const float* __restrict__ Wf2,
                                               const float* __restrict__ bf2,
                                               float* __restrict__ out) {
    int n = blockIdx.x * blockDim.x + threadIdx.x;
    if (n >= NTOK) return;
    float s = bf2[0];
#pragma unroll 16
    for (int k = 0; k < 64; k++) s = fmaf(f[(size_t)n * 64 + k], Wf2[k], s);
    out[n] = 1.0f / (1.0f + expf(-s));
}

// ---------------- launch ----------------
extern "C" void kernel_launch(void* const* d_in, const int* in_sizes, int n_in,
                              void* d_out, int out_size, void* d_ws, size_t ws_size,
                              hipStream_t stream) {
    const float* vis   = (const float*)d_in[0];
    const float* pos   = (const float*)d_in[1];
    const float* grad  = (const float*)d_in[2];
    const float* Bf    = (const float*)d_in[3];
    const float* W_img = (const float*)d_in[4];
    const float* b_img = (const float*)d_in[5];
    const float* W_pos = (const float*)d_in[6];
    const float* b_pos = (const float*)d_in[7];
    const float* Wq = (const float*)d_in[8];  const float* bq = (const float*)d_in[9];
    const float* Wk = (const float*)d_in[10]; const float* bk = (const float*)d_in[11];
    const float* Wv = (const float*)d_in[12]; const float* bv = (const float*)d_in[13];
    const float* Wo = (const float*)d_in[14]; const float* bo = (const float*)d_in[15];
    const float* ln1g = (const float*)d_in[16]; const float* ln1b = (const float*)d_in[17];
    const float* Wr = (const float*)d_in[18]; const float* br = (const float*)d_in[19];
    const float* W1e = (const float*)d_in[20]; const float* b1e = (const float*)d_in[21];
    const float* W2e = (const float*)d_in[22]; const float* b2e = (const float*)d_in[23];
    const float* Wg1 = (const float*)d_in[24]; const float* bg1 = (const float*)d_in[25];
    const float* lngg = (const float*)d_in[26]; const float* lngb = (const float*)d_in[27];
    const float* Wg2 = (const float*)d_in[28]; const float* bg2 = (const float*)d_in[29];
    const float* Wf1 = (const float*)d_in[30]; const float* bf1 = (const float*)d_in[31];
    const float* Wf2 = (const float*)d_in[32]; const float* bf2 = (const float*)d_in[33];

    float* out = (float*)d_out;
    float* outMu = out;
    float* outTh = out + (size_t)NTOK * G_GENES;
    float* outG  = out + (size_t)2 * NTOK * G_GENES;

    float* ws = (float*)d_ws;
    size_t o = 0;
    float* F    = ws + o; o += (size_t)NTOK * 128;
    float* z    = ws + o; o += (size_t)NTOK * DMODEL;
    float* q    = ws + o; o += (size_t)NTOK * DMODEL;
    float* kbuf = ws + o; o += (size_t)NTOK * DMODEL;
    float* vbuf = ws + o; o += (size_t)NTOK * DMODEL;
    float* ctx  = ws + o; o += (size_t)NTOK * DMODEL;
    float* attn = ws + o; o += (size_t)NTOK * DMODEL;
    float* z2   = ws + o; o += (size_t)NTOK * DMODEL;
    float* z3   = ws + o; o += (size_t)NTOK * DMODEL;
    float* gate = ws + o; o += (size_t)NTOK * 4;
    float* S    = ws + o; o += (size_t)NTOK * NTOK;
    // S region reused after attention:
    float* hbuf = S;
    float* tbuf = S + (size_t)NTOK * 1024;
    float* dbuf = tbuf + (size_t)NTOK * DMODEL;
    float* fbuf = dbuf + (size_t)NTOK * DMODEL;

    dim3 blk(256);

    // encoders
    fourier_k<<<NTOK, 64, 0, stream>>>(pos, Bf, F);
    gemm_k<EPI_PLAIN><<<dim3(64, 4, 1), blk, 0, stream>>>(vis, W_img, b_img, z, NTOK, 1024, 256,
                                                          1024, 256, 256, nullptr, 0, nullptr, nullptr, 1024);
    gemm_k<EPI_ACC><<<dim3(64, 4, 1), blk, 0, stream>>>(F, W_pos, b_pos, z, NTOK, 128, 256,
                                                        128, 256, 256, nullptr, 0, nullptr, nullptr, 128);
    // qkv
    gemm_k<EPI_PLAIN><<<dim3(64, 4, 1), blk, 0, stream>>>(z, Wq, bq, q, NTOK, 256, 256,
                                                          256, 256, 256, nullptr, 0, nullptr, nullptr, 256);
    gemm_k<EPI_PLAIN><<<dim3(64, 4, 1), blk, 0, stream>>>(z, Wk, bk, kbuf, NTOK, 256, 256,
                                                          256, 256, 256, nullptr, 0, nullptr, nullptr, 256);
    gemm_k<EPI_PLAIN><<<dim3(64, 4, 1), blk, 0, stream>>>(z, Wv, bv, vbuf, NTOK, 256, 256,
                                                          256, 256, 256, nullptr, 0, nullptr, nullptr, 256);
    // attention (materialized per head)
    hipMemsetAsync(ctx, 0, (size_t)NTOK * DMODEL * sizeof(float), stream);
    for (int h = 0; h < 4; h++) {
        scores_k<<<dim3(64, 64, 1), blk, 0, stream>>>(q, kbuf, S, h);
        softmax_k<<<NTOK, blk, 0, stream>>>(S);
        gemm_k<EPI_ATOMIC><<<dim3(64, 1, 8), blk, 0, stream>>>(S, vbuf + h * 64, nullptr, ctx + h * 64,
                                                               NTOK, NTOK, 64, NTOK, 256, 256,
                                                               nullptr, 0, nullptr, nullptr, 512);
    }
    gemm_k<EPI_PLAIN><<<dim3(64, 4, 1), blk, 0, stream>>>(ctx, Wo, bo, attn, NTOK, 256, 256,
                                                          256, 256, 256, nullptr, 0, nullptr, nullptr, 256);
    ln_k<<<NTOK, blk, 0, stream>>>(z, attn, ln1g, ln1b, z2, 0);
    // MoE (dense over 4 experts, gate has 1 nonzero per token)
    router_k<<<NTOK, 64, 0, stream>>>(z2, grad, Wr, br, gate);
    hipMemcpyAsync(z3, z2, (size_t)NTOK * DMODEL * sizeof(float), hipMemcpyDeviceToDevice, stream);
    for (int e = 0; e < 4; e++) {
        gemm_k<EPI_GELU><<<dim3(64, 16, 1), blk, 0, stream>>>(z2, W1e + (size_t)e * 256 * 1024,
                                                              b1e + (size_t)e * 1024, hbuf,
                                                              NTOK, 256, 1024, 256, 1024, 1024,
                                                              nullptr, 0, nullptr, nullptr, 256);
        gemm_k<EPI_ROWSCALE_ACC><<<dim3(64, 4, 1), blk, 0, stream>>>(hbuf, W2e + (size_t)e * 1024 * 256,
                                                                     b2e + (size_t)e * 256, z3,
                                                                     NTOK, 1024, 256, 1024, 256, 256,
                                                                     gate + e, 4, nullptr, nullptr, 1024);
    }
    // gene decoder
    gemm_k<EPI_PLAIN><<<dim3(64, 4, 1), blk, 0, stream>>>(z3, Wg1, bg1, tbuf, NTOK, 256, 256,
                                                          256, 256, 256, nullptr, 0, nullptr, nullptr, 256);
    ln_k<<<NTOK, blk, 0, stream>>>(tbuf, nullptr, lngg, lngb, dbuf, 1);
    gemm_k<EPI_GENE><<<dim3(64, 63, 1), blk, 0, stream>>>(dbuf, Wg2, bg2, nullptr, NTOK, 256, 4000,
                                                          256, 4000, 0, nullptr, 0, outMu, outTh, 256);
    // functional head
    gemm_k<EPI_GELU><<<dim3(64, 1, 1), blk, 0, stream>>>(z3, Wf1, bf1, fbuf, NTOK, 256, 64,
                                                         256, 64, 64, nullptr, 0, nullptr, nullptr, 256);
    ghead_k<<<NTOK / 256, blk, 0, stream>>>(fbuf, Wf2, bf2, outG);
}

// Round 2
// 996.885 us; speedup vs baseline: 1.6239x; 1.6239x over previous
//
#include <hip/hip_runtime.h>
#include <math.h>

#define NTOK 4096
#define DMODEL 256
#define G_GENES 2000

typedef _Float16 f16;
typedef _Float16 f16x8 __attribute__((ext_vector_type(8)));
typedef float f32x4 __attribute__((ext_vector_type(4)));

// ---------------- helpers ----------------
__device__ __forceinline__ float gelu_exact(float x) {
    return 0.5f * x * (1.0f + erff(x * 0.70710678118654752f));
}
__device__ __forceinline__ float softplus_f(float x) {
    return fmaxf(x, 0.0f) + log1pf(expf(-fabsf(x)));
}

// ---------------- fourier encoding (writes f16 directly into Abig cols 1024..1151) ----------------
__global__ __launch_bounds__(64) void fourier_k(const float* __restrict__ pos,
                                                const float* __restrict__ B,
                                                f16* __restrict__ Abig) {
    int n = blockIdx.x, m = threadIdx.x;
    float xp = 6.283185307179586f *
               (pos[n * 3 + 0] * B[m] + pos[n * 3 + 1] * B[64 + m] + pos[n * 3 + 2] * B[128 + m]);
    Abig[(size_t)n * 1152 + 1024 + m] = (f16)sinf(xp);
    Abig[(size_t)n * 1152 + 1088 + m] = (f16)cosf(xp);
}

// ---------------- vis f32 -> f16 strided into Abig cols 0..1023 ----------------
__global__ __launch_bounds__(256) void cvt_vis_k(const float* __restrict__ vis, f16* __restrict__ Abig) {
    int n = blockIdx.x, t = threadIdx.x;
    float4 v = *(const float4*)(vis + (size_t)n * 1024 + t * 4);
    union { ushort4 u; f16 h[4]; } o;
    o.h[0] = (f16)v.x; o.h[1] = (f16)v.y; o.h[2] = (f16)v.z; o.h[3] = (f16)v.w;
    *(ushort4*)(Abig + (size_t)n * 1152 + t * 4) = o.u;
}

// ---------------- generic f32 -> f16 convert ----------------
__global__ __launch_bounds__(256) void cvt_k(const float* __restrict__ src, f16* __restrict__ dst, int n4) {
    int i = blockIdx.x * 256 + threadIdx.x;
    if (i >= n4) return;
    float4 v = ((const float4*)src)[i];
    union { ushort4 u; f16 h[4]; } o;
    o.h[0] = (f16)v.x; o.h[1] = (f16)v.y; o.h[2] = (f16)v.z; o.h[3] = (f16)v.w;
    ((ushort4*)dst)[i] = o.u;
}

// ---------------- batched transpose-convert: f32 [R,C] -> f16 dst[c*ldo + r] ----------------
struct TD { const float* s; f16* d; int R, C, ldo; };
struct TDs { TD t[17]; };
__global__ __launch_bounds__(256) void tconv_k(TDs ds) {
    TD td = ds.t[blockIdx.z];
    int r0 = blockIdx.x * 32, c0 = blockIdx.y * 32;
    if (r0 >= td.R || c0 >= td.C) return;
    __shared__ float tile[32][33];
    int tx = threadIdx.x & 31, ty = threadIdx.x >> 5;
#pragma unroll
    for (int i = 0; i < 32; i += 8)
        tile[ty + i][tx] = td.s[(size_t)(r0 + ty + i) * td.C + c0 + tx];
    __syncthreads();
#pragma unroll
    for (int i = 0; i < 32; i += 8)
        td.d[(size_t)(c0 + ty + i) * td.ldo + r0 + tx] = (f16)tile[tx][ty + i];
}

// ---------------- f16 transpose (for V^T from qkv buffer) ----------------
__global__ __launch_bounds__(256) void tconvh_k(const f16* __restrict__ src, int ldin,
                                                f16* __restrict__ dst, int ldo) {
    __shared__ f16 tile[32][33];
    int r0 = blockIdx.x * 32, c0 = blockIdx.y * 32;
    int tx = threadIdx.x & 31, ty = threadIdx.x >> 5;
#pragma unroll
    for (int i = 0; i < 32; i += 8)
        tile[ty + i][tx] = src[(size_t)(r0 + ty + i) * ldin + c0 + tx];
    __syncthreads();
#pragma unroll
    for (int i = 0; i < 32; i += 8)
        dst[(size_t)(c0 + ty + i) * ldo + r0 + tx] = tile[tx][ty + i];
}

// ---------------- bias sum ----------------
__global__ __launch_bounds__(256) void addbias_k(const float* a, const float* b, float* o) {
    int t = threadIdx.x;
    o[t] = a[t] + b[t];
}

// ---------------- MFMA f16 GEMM ----------------
// C[M,Ncols] = epi(A[M,K](f16) @ B^T  + bias), B given as [Ncols, K] f16 (transposed).
// BM=128, BN=MTN*32, BK=64; 256 threads = 4 waves in 2x2; wave tile 64 x (MTN*16).
#define EPI_F32 0        // Cf = v (+bias if non-null)
#define EPI_DUAL 1       // Cf = v+bias; Ch = f16(v+bias)
#define EPI_F16 2        // Ch = f16(v+bias)
#define EPI_GELU_F16 3   // Ch = f16(gelu(v+bias))
#define EPI_SCALE_F16 4  // Ch = f16(v*0.125)
#define EPI_SPLIT 5      // Cf[z*M*ldc + ...] = v   (split-K partials)
#define EPI_GENE 6       // softplus -> outMu/outTheta

template <int MTN, int EPI>
__global__ __launch_bounds__(256) void bgemm_k(
    const f16* __restrict__ A, int lda,
    const f16* __restrict__ B, int ldb,
    const float* __restrict__ bias,
    float* __restrict__ Cf, f16* __restrict__ Ch, int ldc,
    int M, int Ncols, int K, int kChunk,
    float* __restrict__ outMu, float* __restrict__ outTheta) {
    constexpr int BN = MTN * 32;
    __shared__ f16 As[128][72];
    __shared__ f16 Bs[BN][72];
    const int tid = threadIdx.x;
    const int m0 = blockIdx.x * 128;
    const int n0 = blockIdx.y * BN;
    const int w = tid >> 6, lane = tid & 63;
    const int wr = w >> 1, wc = w & 1;
    const int ln = lane & 15, lg = lane >> 4;
    const int k_begin = blockIdx.z * kChunk;
    int k_end = k_begin + kChunk;
    if (k_end > K) k_end = K;

    const int sr = tid >> 3;        // 0..31
    const int sc = (tid & 7) * 8;   // f16 offset 0..56

    f32x4 acc[4][MTN];
    f32x4 zf = {0.f, 0.f, 0.f, 0.f};
#pragma unroll
    for (int i = 0; i < 4; i++)
#pragma unroll
        for (int j = 0; j < MTN; j++) acc[i][j] = zf;

    for (int k0 = k_begin; k0 < k_end; k0 += 64) {
#pragma unroll
        for (int i = 0; i < 4; i++) {
            int r = sr + i * 32;
            uint4 v = *(const uint4*)(A + (size_t)(m0 + r) * lda + k0 + sc);
            *(uint2*)&As[r][sc] = make_uint2(v.x, v.y);
            *(uint2*)&As[r][sc + 4] = make_uint2(v.z, v.w);
        }
#pragma unroll
        for (int i = 0; i < MTN; i++) {
            int r = sr + i * 32;
            uint4 v = make_uint4(0, 0, 0, 0);
            if (n0 + r < Ncols) v = *(const uint4*)(B + (size_t)(n0 + r) * ldb + k0 + sc);
            *(uint2*)&Bs[r][sc] = make_uint2(v.x, v.y);
            *(uint2*)&Bs[r][sc + 4] = make_uint2(v.z, v.w);
        }
        __syncthreads();
#pragma unroll
        for (int ks = 0; ks < 64; ks += 32) {
            f16x8 a[4], b[MTN];
#pragma unroll
            for (int t = 0; t < 4; t++) {
                const f16* p = &As[wr * 64 + t * 16 + ln][ks + lg * 8];
                union { f16x8 f; uint2 u[2]; } tmp;
                tmp.u[0] = *(const uint2*)p;
                tmp.u[1] = *(const uint2*)(p + 4);
                a[t] = tmp.f;
            }
#pragma unroll
            for (int t = 0; t < MTN; t++) {
                const f16* p = &Bs[wc * (MTN * 16) + t * 16 + ln][ks + lg * 8];
                union { f16x8 f; uint2 u[2]; } tmp;
                tmp.u[0] = *(const uint2*)p;
                tmp.u[1] = *(const uint2*)(p + 4);
                b[t] = tmp.f;
            }
#pragma unroll
            for (int tm = 0; tm < 4; tm++)
#pragma unroll
                for (int tn = 0; tn < MTN; tn++)
                    acc[tm][tn] = __builtin_amdgcn_mfma_f32_16x16x32_f16(a[tm], b[tn], acc[tm][tn], 0, 0, 0);
        }
        __syncthreads();
    }

#pragma unroll
    for (int tm = 0; tm < 4; tm++) {
#pragma unroll
        for (int tn = 0; tn < MTN; tn++) {
            int col = n0 + wc * (MTN * 16) + tn * 16 + ln;
            if (col >= Ncols) continue;
#pragma unroll
            for (int i = 0; i < 4; i++) {
                int row = m0 + wr * 64 + tm * 16 + lg * 4 + i;
                float v = acc[tm][tn][i];
                size_t idx = (size_t)row * ldc + col;
                if (EPI == EPI_F32) {
                    if (bias) v += bias[col];
                    Cf[idx] = v;
                } else if (EPI == EPI_DUAL) {
                    v += bias[col];
                    Cf[idx] = v;
                    Ch[idx] = (f16)v;
                } else if (EPI == EPI_F16) {
                    v += bias[col];
                    Ch[idx] = (f16)v;
                } else if (EPI == EPI_GELU_F16) {
                    v += bias[col];
                    Ch[idx] = (f16)gelu_exact(v);
                } else if (EPI == EPI_SCALE_F16) {
                    Ch[idx] = (f16)(v * 0.125f);
                } else if (EPI == EPI_SPLIT) {
                    Cf[(size_t)blockIdx.z * M * ldc + idx] = v;
                } else if (EPI == EPI_GENE) {
                    v += bias[col];
                    float sp = softplus_f(v);
                    size_t gi = (size_t)row * G_GENES + (col >> 1);
                    if (col & 1) outTheta[gi] = sp + 1e-6f;
                    else outMu[gi] = sp;
                }
            }
        }
    }
}

// ---------------- row softmax over 4096 cols, f16 in/out ----------------
__global__ __launch_bounds__(256) void softmax_k(f16* __restrict__ S) {
    __shared__ float sm[4];
    size_t base = (size_t)blockIdx.x * 4096;
    int t = threadIdx.x;
    union { uint4 q; f16 h[8]; } u0, u1;
    u0.q = *(const uint4*)(S + base + t * 8);
    u1.q = *(const uint4*)(S + base + 2048 + t * 8);
    float v[16];
    float mx = -3.4e38f;
#pragma unroll
    for (int i = 0; i < 8; i++) { v[i] = (float)u0.h[i]; v[8 + i] = (float)u1.h[i]; }
#pragma unroll
    for (int i = 0; i < 16; i++) mx = fmaxf(mx, v[i]);
    for (int off = 32; off; off >>= 1) mx = fmaxf(mx, __shfl_down(mx, off));
    if ((t & 63) == 0) sm[t >> 6] = mx;
    __syncthreads();
    mx = fmaxf(fmaxf(sm[0], sm[1]), fmaxf(sm[2], sm[3]));
    float s = 0.0f;
#pragma unroll
    for (int i = 0; i < 16; i++) { v[i] = __expf(v[i] - mx); s += v[i]; }
    for (int off = 32; off; off >>= 1) s += __shfl_down(s, off);
    __syncthreads();
    if ((t & 63) == 0) sm[t >> 6] = s;
    __syncthreads();
    float inv = 1.0f / (sm[0] + sm[1] + sm[2] + sm[3]);
#pragma unroll
    for (int i = 0; i < 8; i++) { u0.h[i] = (f16)(v[i] * inv); u1.h[i] = (f16)(v[8 + i] * inv); }
    *(uint4*)(S + base + t * 8) = u0.q;
    *(uint4*)(S + base + 2048 + t * 8) = u1.q;
}

// ---------------- PV split-K reduce: ctx[m, h*64+d] = sum_z pvp[z][m][d] ----------------
__global__ __launch_bounds__(256) void pvred_k(const float* __restrict__ pvp, float* __restrict__ ctx, int head) {
    int i = (blockIdx.x * 256 + threadIdx.x) * 4;   // over 4096*64
    float4 s = {0.f, 0.f, 0.f, 0.f};
#pragma unroll
    for (int z = 0; z < 8; z++) {
        float4 p = *(const float4*)(pvp + (size_t)z * (NTOK * 64) + i);
        s.x += p.x; s.y += p.y; s.z += p.z; s.w += p.w;
    }
    int row = i >> 6, d = i & 63;
    *(float4*)(ctx + (size_t)row * 256 + head * 64 + d) = s;
}

// ---------------- MoE split-K reduce with gate: z3 += gate_e * (sum_z part + b2) ----------------
__global__ __launch_bounds__(256) void moered_k(const float* __restrict__ part, const float* __restrict__ b2,
                                                const float* __restrict__ gate, int e, float* __restrict__ z3) {
    int i = (blockIdx.x * 256 + threadIdx.x) * 4;   // over 4096*256
    float4 s = {0.f, 0.f, 0.f, 0.f};
#pragma unroll
    for (int z = 0; z < 4; z++) {
        float4 p = *(const float4*)(part + (size_t)z * (NTOK * 256) + i);
        s.x += p.x; s.y += p.y; s.z += p.z; s.w += p.w;
    }
    int row = i >> 8, c = i & 255;
    float g = gate[row * 4 + e];
    float4 b = *(const float4*)(b2 + c);
    float4 o = *(const float4*)(z3 + i);
    o.x += g * (s.x + b.x); o.y += g * (s.y + b.y);
    o.z += g * (s.z + b.z); o.w += g * (s.w + b.w);
    *(float4*)(z3 + i) = o;
}

// ---------------- layernorm, dual fp32/f16 outputs ----------------
__global__ __launch_bounds__(256) void ln_k(const float* __restrict__ X,
                                            const float* __restrict__ R,
                                            const float* __restrict__ gam,
                                            const float* __restrict__ bet,
                                            float* __restrict__ Of, f16* __restrict__ Oh, int doGelu) {
    __shared__ float sm[4];
    int n = blockIdx.x, c = threadIdx.x;
    float x = X[(size_t)n * DMODEL + c];
    if (R) x += R[(size_t)n * DMODEL + c];
    float s = x;
    for (int off = 32; off; off >>= 1) s += __shfl_down(s, off);
    if ((c & 63) == 0) sm[c >> 6] = s;
    __syncthreads();
    float mean = (sm[0] + sm[1] + sm[2] + sm[3]) * (1.0f / DMODEL);
    float d = x - mean;
    float s2 = d * d;
    for (int off = 32; off; off >>= 1) s2 += __shfl_down(s2, off);
    __syncthreads();
    if ((c & 63) == 0) sm[c >> 6] = s2;
    __syncthreads();
    float var = (sm[0] + sm[1] + sm[2] + sm[3]) * (1.0f / DMODEL);
    float y = d * rsqrtf(var + 1e-5f) * gam[c] + bet[c];
    if (doGelu) y = gelu_exact(y);
    size_t idx = (size_t)n * DMODEL + c;
    if (Of) Of[idx] = y;
    if (Oh) Oh[idx] = (f16)y;
}

// ---------------- router: top-1 gate ----------------
__global__ __launch_bounds__(64) void router_k(const float* __restrict__ z2,
                                               const float* __restrict__ grad,
                                               const float* __restrict__ Wr,
                                               const float* __restrict__ br,
                                               float* __restrict__ gate) {
    int n = blockIdx.x, t = threadIdx.x;
    float p0 = 0, p1 = 0, p2 = 0, p3 = 0;
#pragma unroll
    for (int i = 0; i < 4; i++) {
        int d = t + i * 64;
        float zv = z2[(size_t)n * DMODEL + d];
        p0 = fmaf(zv, Wr[d * 4 + 0], p0);
        p1 = fmaf(zv, Wr[d * 4 + 1], p1);
        p2 = fmaf(zv, Wr[d * 4 + 2], p2);
        p3 = fmaf(zv, Wr[d * 4 + 3], p3);
    }
    for (int off = 32; off; off >>= 1) {
        p0 += __shfl_down(p0, off);
        p1 += __shfl_down(p1, off);
        p2 += __shfl_down(p2, off);
        p3 += __shfl_down(p3, off);
    }
    if (t == 0) {
        float gv = grad[n];
        float l[4];
        l[0] = p0 + gv * Wr[256 * 4 + 0] + br[0];
        l[1] = p1 + gv * Wr[256 * 4 + 1] + br[1];
        l[2] = p2 + gv * Wr[256 * 4 + 2] + br[2];
        l[3] = p3 + gv * Wr[256 * 4 + 3] + br[3];
        float mx = fmaxf(fmaxf(l[0], l[1]), fmaxf(l[2], l[3]));
        float e[4], s = 0;
#pragma unroll
        for (int i = 0; i < 4; i++) { e[i] = __expf(l[i] - mx); s += e[i]; }
        int am = 0;
        float best = l[0];
#pragma unroll
        for (int i = 1; i < 4; i++)
            if (l[i] > best) { best = l[i]; am = i; }
        float p = e[am] / s;
#pragma unroll
        for (int i = 0; i < 4; i++) gate[(size_t)n * 4 + i] = (i == am) ? p : 0.0f;
    }
}

// ---------------- functional head final ----------------
__global__ __launch_bounds__(256) void ghead_k(const f16* __restrict__ f,
                                               const float* __restrict__ Wf2,
                                               const float* __restrict__ bf2,
                                               float* __restrict__ out) {
    int n = blockIdx.x * 256 + threadIdx.x;
    float s = bf2[0];
#pragma unroll 16
    for (int k = 0; k < 64; k++) s = fmaf((float)f[(size_t)n * 64 + k], Wf2[k], s);
    out[n] = 1.0f / (1.0f + expf(-s));
}

// ---------------- launch ----------------
extern "C" void kernel_launch(void* const* d_in, const int* in_sizes, int n_in,
                              void* d_out, int out_size, void* d_ws, size_t ws_size,
                              hipStream_t stream) {
    const float* vis   = (const float*)d_in[0];
    const float* pos   = (const float*)d_in[1];
    const float* grad  = (const float*)d_in[2];
    const float* Bf    = (const float*)d_in[3];
    const float* W_img = (const float*)d_in[4];
    const float* b_img = (const float*)d_in[5];
    const float* W_pos = (const float*)d_in[6];
    const float* b_pos = (const float*)d_in[7];
    const float* Wq = (const float*)d_in[8];  const float* bq = (const float*)d_in[9];
    const float* Wk = (const float*)d_in[10]; const float* bk = (const float*)d_in[11];
    const float* Wv = (const float*)d_in[12]; const float* bv = (const float*)d_in[13];
    const float* Wo = (const float*)d_in[14]; const float* bo = (const float*)d_in[15];
    const float* ln1g = (const float*)d_in[16]; const float* ln1b = (const float*)d_in[17];
    const float* Wr = (const float*)d_in[18]; const float* br = (const float*)d_in[19];
    const float* W1e = (const float*)d_in[20]; const float* b1e = (const float*)d_in[21];
    const float* W2e = (const float*)d_in[22]; const float* b2e = (const float*)d_in[23];
    const float* Wg1 = (const float*)d_in[24]; const float* bg1 = (const float*)d_in[25];
    const float* lngg = (const float*)d_in[26]; const float* lngb = (const float*)d_in[27];
    const float* Wg2 = (const float*)d_in[28]; const float* bg2 = (const float*)d_in[29];
    const float* Wf1 = (const float*)d_in[30]; const float* bf1 = (const float*)d_in[31];
    const float* Wf2 = (const float*)d_in[32]; const float* bf2 = (const float*)d_in[33];

    float* out = (float*)d_out;
    float* outMu = out;
    float* outTh = out + (size_t)NTOK * G_GENES;
    float* outG  = out + (size_t)2 * NTOK * G_GENES;

    // ---- workspace layout ----
    char* base = (char*)d_ws;
    size_t off = 0;
    auto A8 = [&](size_t bytes) { char* p = base + off; off += (bytes + 255) & ~(size_t)255; return p; };

    // 12 MB multi-use region: Abig (enc A, 9.4MB) / pvp (attn partials, 8MB) / hbf (MoE mid, 8MB) + tbuf @ +8MB
    char* big = A8(12 * 1024 * 1024);
    f16*   Abig = (f16*)big;
    float* pvp  = (float*)big;
    f16*   hbf  = (f16*)big;
    float* tbuf = (float*)(big + 8 * 1024 * 1024);

    f16* WtEnc = (f16*)A8((size_t)256 * 1152 * 2);
    f16* Wqkvt = (f16*)A8((size_t)768 * 256 * 2);
    f16* Wot   = (f16*)A8((size_t)256 * 256 * 2);
    f16* W1t   = (f16*)A8((size_t)4 * 1024 * 256 * 2);
    f16* W2t   = (f16*)A8((size_t)4 * 256 * 1024 * 2);
    f16* Wg1t  = (f16*)A8((size_t)256 * 256 * 2);
    f16* Wg2t  = (f16*)A8((size_t)4000 * 256 * 2);
    f16* Wf1t  = (f16*)A8((size_t)64 * 256 * 2);
    float* benc    = (float*)A8(256 * 4);
    float* biasqkv = (float*)A8(768 * 4);
    f16* qkvbf = (f16*)A8((size_t)NTOK * 768 * 2);
    f16* Vt    = (f16*)A8((size_t)256 * NTOK * 2);
    f16* S     = (f16*)A8((size_t)NTOK * NTOK * 2);   // reused as MoE partials (fp32, 16MB)
    float* moePart = (float*)S;
    float* z    = (float*)A8((size_t)NTOK * DMODEL * 4);
    float* z2   = (float*)A8((size_t)NTOK * DMODEL * 4);
    float* z3   = (float*)A8((size_t)NTOK * DMODEL * 4);
    float* ctx  = (float*)A8((size_t)NTOK * DMODEL * 4);
    float* attn = (float*)A8((size_t)NTOK * DMODEL * 4);
    f16* zbf    = (f16*)A8((size_t)NTOK * DMODEL * 2);
    f16* z2bf   = (f16*)A8((size_t)NTOK * DMODEL * 2);
    f16* z3bf   = (f16*)A8((size_t)NTOK * DMODEL * 2);
    f16* ctxbf  = (f16*)A8((size_t)NTOK * DMODEL * 2);
    f16* dbufbf = (f16*)A8((size_t)NTOK * DMODEL * 2);
    f16* fbf    = (f16*)A8((size_t)NTOK * 64 * 2);
    float* gate = (float*)A8((size_t)NTOK * 4 * 4);

    dim3 blk(256);

    // ---- weight prep (one batched transpose-convert) ----
    TDs td;
    int nd = 0;
    auto addT = [&](const float* s, f16* d, int R, int C, int ldo) { td.t[nd++] = TD{s, d, R, C, ldo}; };
    addT(W_img, WtEnc, 1024, 256, 1152);
    addT(W_pos, WtEnc + 1024, 128, 256, 1152);
    addT(Wq, Wqkvt, 256, 256, 256);
    addT(Wk, Wqkvt + 256 * 256, 256, 256, 256);
    addT(Wv, Wqkvt + 512 * 256, 256, 256, 256);
    addT(Wo, Wot, 256, 256, 256);
    for (int e = 0; e < 4; e++) addT(W1e + (size_t)e * 262144, W1t + (size_t)e * 262144, 256, 1024, 256);
    for (int e = 0; e < 4; e++) addT(W2e + (size_t)e * 262144, W2t + (size_t)e * 262144, 1024, 256, 1024);
    addT(Wg1, Wg1t, 256, 256, 256);
    addT(Wg2, Wg2t, 256, 4000, 256);
    addT(Wf1, Wf1t, 256, 64, 256);
    tconv_k<<<dim3(32, 125, 17), blk, 0, stream>>>(td);
    addbias_k<<<1, blk, 0, stream>>>(b_img, b_pos, benc);
    hipMemcpyAsync(biasqkv, bq, 256 * 4, hipMemcpyDeviceToDevice, stream);
    hipMemcpyAsync(biasqkv + 256, bk, 256 * 4, hipMemcpyDeviceToDevice, stream);
    hipMemcpyAsync(biasqkv + 512, bv, 256 * 4, hipMemcpyDeviceToDevice, stream);

    // ---- encoder: z = [vis, fourier] @ [W_img; W_pos] + (b_img+b_pos) ----
    cvt_vis_k<<<NTOK, blk, 0, stream>>>(vis, Abig);
    fourier_k<<<NTOK, 64, 0, stream>>>(pos, Bf, Abig);
    bgemm_k<4, EPI_DUAL><<<dim3(32, 2, 1), blk, 0, stream>>>(
        Abig, 1152, WtEnc, 1152, benc, z, zbf, 256, NTOK, 256, 1152, 1152, nullptr, nullptr);

    // ---- fused QKV ----
    bgemm_k<4, EPI_F16><<<dim3(32, 6, 1), blk, 0, stream>>>(
        zbf, 256, Wqkvt, 256, biasqkv, nullptr, qkvbf, 768, NTOK, 768, 256, 256, nullptr, nullptr);
    tconvh_k<<<dim3(128, 8, 1), blk, 0, stream>>>(qkvbf + 512, 768, Vt, 4096);

    // ---- attention per head ----
    for (int h = 0; h < 4; h++) {
        bgemm_k<4, EPI_SCALE_F16><<<dim3(32, 32, 1), blk, 0, stream>>>(
            qkvbf + h * 64, 768, qkvbf + 256 + h * 64, 768, nullptr,
            nullptr, S, 4096, NTOK, NTOK, 64, 64, nullptr, nullptr);
        softmax_k<<<NTOK, blk, 0, stream>>>(S);
        bgemm_k<2, EPI_SPLIT><<<dim3(32, 1, 8), blk, 0, stream>>>(
            S, 4096, Vt + (size_t)h * 64 * 4096, 4096, nullptr,
            pvp, nullptr, 64, NTOK, 64, 4096, 512, nullptr, nullptr);
        pvred_k<<<256, blk, 0, stream>>>(pvp, ctx, h);
    }
    cvt_k<<<1024, blk, 0, stream>>>(ctx, ctxbf, NTOK * DMODEL / 4);
    bgemm_k<4, EPI_F32><<<dim3(32, 2, 1), blk, 0, stream>>>(
        ctxbf, 256, Wot, 256, bo, attn, nullptr, 256, NTOK, 256, 256, 256, nullptr, nullptr);
    ln_k<<<NTOK, blk, 0, stream>>>(z, attn, ln1g, ln1b, z2, z2bf, 0);

    // ---- MoE (dense over 4 experts; gate has 1 nonzero/token) ----
    router_k<<<NTOK, 64, 0, stream>>>(z2, grad, Wr, br, gate);
    hipMemcpyAsync(z3, z2, (size_t)NTOK * DMODEL * 4, hipMemcpyDeviceToDevice, stream);
    for (int e = 0; e < 4; e++) {
        bgemm_k<4, EPI_GELU_F16><<<dim3(32, 8, 1), blk, 0, stream>>>(
            z2bf, 256, W1t + (size_t)e * 262144, 256, b1e + e * 1024,
            nullptr, hbf, 1024, NTOK, 1024, 256, 256, nullptr, nullptr);
        bgemm_k<4, EPI_SPLIT><<<dim3(32, 2, 4), blk, 0, stream>>>(
            hbf, 1024, W2t + (size_t)e * 262144, 1024, nullptr,
            moePart, nullptr, 256, NTOK, 256, 1024, 256, nullptr, nullptr);
        moered_k<<<1024, blk, 0, stream>>>(moePart, b2e + e * 256, gate, e, z3);
    }
    cvt_k<<<1024, blk, 0, stream>>>(z3, z3bf, NTOK * DMODEL / 4);

    // ---- gene decoder ----
    bgemm_k<4, EPI_F32><<<dim3(32, 2, 1), blk, 0, stream>>>(
        z3bf, 256, Wg1t, 256, bg1, tbuf, nullptr, 256, NTOK, 256, 256, 256, nullptr, nullptr);
    ln_k<<<NTOK, blk, 0, stream>>>(tbuf, nullptr, lngg, lngb, nullptr, dbufbf, 1);
    bgemm_k<4, EPI_GENE><<<dim3(32, 32, 1), blk, 0, stream>>>(
        dbufbf, 256, Wg2t, 256, bg2, nullptr, nullptr, 4000, NTOK, 4000, 256, 256, outMu, outTh);

    // ---- functional head ----
    bgemm_k<2, EPI_GELU_F16><<<dim3(32, 1, 1), blk, 0, stream>>>(
        z3bf, 256, Wf1t, 256, bf1, nullptr, fbf, 64, NTOK, 64, 256, 256, nullptr, nullptr);
    ghead_k<<<NTOK / 256, blk, 0, stream>>>(fbf, Wf2, bf2, outG);
}

// Round 3
// 581.305 us; speedup vs baseline: 2.7848x; 1.7149x over previous
//
#include <hip/hip_runtime.h>
#include <math.h>

#define NTOK 4096
#define DMODEL 256
#define G_GENES 2000

typedef _Float16 f16;
typedef _Float16 f16x8 __attribute__((ext_vector_type(8)));
typedef float f32x4 __attribute__((ext_vector_type(4)));

// ---------------- helpers ----------------
__device__ __forceinline__ float gelu_exact(float x) {
    return 0.5f * x * (1.0f + erff(x * 0.70710678118654752f));
}
__device__ __forceinline__ float softplus_fast(float x) {
    return fmaxf(x, 0.0f) + __logf(1.0f + __expf(-fabsf(x)));
}

// ---------------- fourier encoding (writes f16 into Abig cols 1024..1151) ----------------
__global__ __launch_bounds__(64) void fourier_k(const float* __restrict__ pos,
                                                const float* __restrict__ B,
                                                f16* __restrict__ Abig) {
    int n = blockIdx.x, m = threadIdx.x;
    float xp = 6.283185307179586f *
               (pos[n * 3 + 0] * B[m] + pos[n * 3 + 1] * B[64 + m] + pos[n * 3 + 2] * B[128 + m]);
    Abig[(size_t)n * 1152 + 1024 + m] = (f16)sinf(xp);
    Abig[(size_t)n * 1152 + 1088 + m] = (f16)cosf(xp);
}

// ---------------- vis f32 -> f16 strided into Abig cols 0..1023 ----------------
__global__ __launch_bounds__(256) void cvt_vis_k(const float* __restrict__ vis, f16* __restrict__ Abig) {
    int n = blockIdx.x, t = threadIdx.x;
    float4 v = *(const float4*)(vis + (size_t)n * 1024 + t * 4);
    union { ushort4 u; f16 h[4]; } o;
    o.h[0] = (f16)v.x; o.h[1] = (f16)v.y; o.h[2] = (f16)v.z; o.h[3] = (f16)v.w;
    *(ushort4*)(Abig + (size_t)n * 1152 + t * 4) = o.u;
}

// ---------------- batched transpose-convert: f32 [R,C] -> f16 dst[c*ldo + r] ----------------
struct TD { const float* s; f16* d; int R, C, ldo; };
struct TDs { TD t[17]; };
__global__ __launch_bounds__(256) void tconv_k(TDs ds) {
    TD td = ds.t[blockIdx.z];
    int r0 = blockIdx.x * 32, c0 = blockIdx.y * 32;
    if (r0 >= td.R || c0 >= td.C) return;
    __shared__ float tile[32][33];
    int tx = threadIdx.x & 31, ty = threadIdx.x >> 5;
#pragma unroll
    for (int i = 0; i < 32; i += 8)
        tile[ty + i][tx] = td.s[(size_t)(r0 + ty + i) * td.C + c0 + tx];
    __syncthreads();
#pragma unroll
    for (int i = 0; i < 32; i += 8)
        td.d[(size_t)(c0 + ty + i) * td.ldo + r0 + tx] = (f16)tile[tx][ty + i];
}

// ---------------- bias sum ----------------
__global__ __launch_bounds__(256) void addbias_k(const float* a, const float* b, float* o) {
    int t = threadIdx.x;
    o[t] = a[t] + b[t];
}

// ---------------- MFMA f16 GEMM ----------------
// C[M,Ncols] = epi(A[M,K](f16) @ B^T + bias), B given as [Ncols, K] f16.
// BM=128, BN=MTN*32, BK=64; 256 threads = 4 waves in 2x2; wave tile 64 x (MTN*16).
// ZEXP=1: blockIdx.z selects expert; pointers advance by e* strides.
#define EPI_F32 0        // Cf = v (+bias if non-null)
#define EPI_DUAL 1       // Cf = v+bias; Ch = f16(v+bias)
#define EPI_F16 2        // Ch = f16(v+bias)
#define EPI_GELU_F16 3   // Ch = f16(gelu(v+bias))
#define EPI_GENE 4       // softplus -> outMu/outTheta (LDS-coalesced, MTN must be 4)

template <int MTN, int EPI, int ZEXP>
__global__ __launch_bounds__(256) void bgemm_k(
    const f16* __restrict__ A, int lda,
    const f16* __restrict__ B, int ldb,
    const float* __restrict__ bias,
    float* __restrict__ Cf, f16* __restrict__ Ch, int ldc,
    int M, int Ncols, int K,
    size_t eA, size_t eB, size_t eBias, size_t eC,
    float* __restrict__ outMu, float* __restrict__ outTheta) {
    constexpr int BN = MTN * 32;
    __shared__ __align__(16) char smem[(128 + BN) * 72 * 2];
    f16 (*As)[72] = (f16(*)[72])smem;
    f16 (*Bs)[72] = (f16(*)[72])(smem + (size_t)128 * 72 * 2);

    if (ZEXP) {
        int e = blockIdx.z;
        A += (size_t)e * eA;
        B += (size_t)e * eB;
        if (bias) bias += (size_t)e * eBias;
        if (Cf) Cf += (size_t)e * eC;
        if (Ch) Ch += (size_t)e * eC;
    }

    const int tid = threadIdx.x;
    const int m0 = blockIdx.x * 128;
    const int n0 = blockIdx.y * BN;
    const int w = tid >> 6, lane = tid & 63;
    const int wr = w >> 1, wc = w & 1;
    const int ln = lane & 15, lg = lane >> 4;

    const int sr = tid >> 3;        // 0..31
    const int sc = (tid & 7) * 8;   // f16 offset 0..56

    f32x4 acc[4][MTN];
    f32x4 zf = {0.f, 0.f, 0.f, 0.f};
#pragma unroll
    for (int i = 0; i < 4; i++)
#pragma unroll
        for (int j = 0; j < MTN; j++) acc[i][j] = zf;

    for (int k0 = 0; k0 < K; k0 += 64) {
#pragma unroll
        for (int i = 0; i < 4; i++) {
            int r = sr + i * 32;
            uint4 v = *(const uint4*)(A + (size_t)(m0 + r) * lda + k0 + sc);
            *(uint2*)&As[r][sc] = make_uint2(v.x, v.y);
            *(uint2*)&As[r][sc + 4] = make_uint2(v.z, v.w);
        }
#pragma unroll
        for (int i = 0; i < MTN; i++) {
            int r = sr + i * 32;
            uint4 v = make_uint4(0, 0, 0, 0);
            if (n0 + r < Ncols) v = *(const uint4*)(B + (size_t)(n0 + r) * ldb + k0 + sc);
            *(uint2*)&Bs[r][sc] = make_uint2(v.x, v.y);
            *(uint2*)&Bs[r][sc + 4] = make_uint2(v.z, v.w);
        }
        __syncthreads();
#pragma unroll
        for (int ks = 0; ks < 64; ks += 32) {
            f16x8 a[4], b[MTN];
#pragma unroll
            for (int t = 0; t < 4; t++) {
                const f16* p = &As[wr * 64 + t * 16 + ln][ks + lg * 8];
                union { f16x8 f; uint2 u[2]; } tmp;
                tmp.u[0] = *(const uint2*)p;
                tmp.u[1] = *(const uint2*)(p + 4);
                a[t] = tmp.f;
            }
#pragma unroll
            for (int t = 0; t < MTN; t++) {
                const f16* p = &Bs[wc * (MTN * 16) + t * 16 + ln][ks + lg * 8];
                union { f16x8 f; uint2 u[2]; } tmp;
                tmp.u[0] = *(const uint2*)p;
                tmp.u[1] = *(const uint2*)(p + 4);
                b[t] = tmp.f;
            }
#pragma unroll
            for (int tm = 0; tm < 4; tm++)
#pragma unroll
                for (int tn = 0; tn < MTN; tn++)
                    acc[tm][tn] = __builtin_amdgcn_mfma_f32_16x16x32_f16(a[tm], b[tn], acc[tm][tn], 0, 0, 0);
        }
        __syncthreads();
    }

    if (EPI == EPI_GENE) {
        // coalesced epilogue: stage 32x128 f32 slices in LDS, write 8-consecutive-gene chunks
        float bval[MTN];
#pragma unroll
        for (int tn = 0; tn < MTN; tn++) {
            int col = n0 + wc * (MTN * 16) + tn * 16 + ln;
            bval[tn] = (col < Ncols) ? bias[col] : 0.0f;
        }
        float* Cs = (float*)smem;   // 32 x 132 = 16.5 KB, fits in As region
        const int rrow = tid >> 3;  // 0..31
        const int rseg = tid & 7;   // 0..7
#pragma unroll
        for (int tm = 0; tm < 4; tm++) {
            __syncthreads();
#pragma unroll
            for (int tn = 0; tn < MTN; tn++) {
                int lc = wc * (MTN * 16) + tn * 16 + ln;
#pragma unroll
                for (int i = 0; i < 4; i++) {
                    int lr = wr * 16 + lg * 4 + i;
                    Cs[lr * 132 + lc] = acc[tm][tn][i] + bval[tn];
                }
            }
            __syncthreads();
            int grow = m0 + ((rrow >> 4) * 64) + tm * 16 + (rrow & 15);
            const float* cr = &Cs[rrow * 132 + rseg * 16];
            float mu[8], th[8];
#pragma unroll
            for (int g = 0; g < 8; g++) {
                mu[g] = softplus_fast(cr[2 * g]);
                th[g] = softplus_fast(cr[2 * g + 1]) + 1e-6f;
            }
            int gbase = (n0 + rseg * 16) >> 1;
            float* mp = outMu + (size_t)grow * G_GENES + gbase;
            float* tp = outTheta + (size_t)grow * G_GENES + gbase;
            if (gbase + 8 <= G_GENES) {
                *(float4*)mp = make_float4(mu[0], mu[1], mu[2], mu[3]);
                *(float4*)(mp + 4) = make_float4(mu[4], mu[5], mu[6], mu[7]);
                *(float4*)tp = make_float4(th[0], th[1], th[2], th[3]);
                *(float4*)(tp + 4) = make_float4(th[4], th[5], th[6], th[7]);
            } else {
#pragma unroll
                for (int g = 0; g < 8; g++)
                    if (gbase + g < G_GENES) { mp[g] = mu[g]; tp[g] = th[g]; }
            }
        }
        return;
    }

#pragma unroll
    for (int tm = 0; tm < 4; tm++) {
#pragma unroll
        for (int tn = 0; tn < MTN; tn++) {
            int col = n0 + wc * (MTN * 16) + tn * 16 + ln;
            if (col >= Ncols) continue;
#pragma unroll
            for (int i = 0; i < 4; i++) {
                int row = m0 + wr * 64 + tm * 16 + lg * 4 + i;
                float v = acc[tm][tn][i];
                size_t idx = (size_t)row * ldc + col;
                if (EPI == EPI_F32) {
                    if (bias) v += bias[col];
                    Cf[idx] = v;
                } else if (EPI == EPI_DUAL) {
                    v += bias[col];
                    Cf[idx] = v;
                    Ch[idx] = (f16)v;
                } else if (EPI == EPI_F16) {
                    v += bias[col];
                    Ch[idx] = (f16)v;
                } else if (EPI == EPI_GELU_F16) {
                    v += bias[col];
                    Ch[idx] = (f16)gelu_exact(v);
                }
            }
        }
    }
}

// ---------------- flash attention ----------------
// grid (64 q-tiles, 4 heads), 256 threads = 4 waves; wave owns 16 Q rows.
// qkv: [4096, 768] f16 (Q | K | V each 256 = 4 heads x 64). ctxbf: [4096, 256] f16.
__global__ __launch_bounds__(256) void flash_k(const f16* __restrict__ qkv,
                                               f16* __restrict__ ctxbf) {
    __shared__ f16 Ks[64][80];       // [kv][feat]
    __shared__ f16 Vts[64][80];      // [d][kv]  (transposed)
    __shared__ f16 Ps[4][16][80];    // per-wave P rows
    const int tid = threadIdx.x;
    const int w = tid >> 6, lane = tid & 63;
    const int ln = lane & 15, quad = lane >> 4;
    const int q0 = blockIdx.x * 64;
    const int hq = blockIdx.y * 64;

    // Q fragments (A-layout: m=ln, k=quad*8+j (+32c)), held for whole kernel
    f16x8 qfrag[2];
    {
        const f16* qp = qkv + (size_t)(q0 + w * 16 + ln) * 768 + hq + quad * 8;
        union { f16x8 f; uint4 u; } t0, t1;
        t0.u = *(const uint4*)qp;
        t1.u = *(const uint4*)(qp + 32);
        qfrag[0] = t0.f; qfrag[1] = t1.f;
    }

    const int srow = tid >> 2;        // 0..63
    const int scol = (tid & 3) * 16;  // 0,16,32,48

    float m_run[4], l_run[4];
    f32x4 Oacc[4];
#pragma unroll
    for (int i = 0; i < 4; i++) {
        m_run[i] = -1e30f; l_run[i] = 0.0f;
        Oacc[i] = (f32x4){0.f, 0.f, 0.f, 0.f};
    }

    // prefetch tile 0
    uint4 kreg[2], vreg[2];
    {
        const f16* kp = qkv + (size_t)srow * 768 + 256 + hq + scol;
        const f16* vp = qkv + (size_t)srow * 768 + 512 + hq + scol;
        kreg[0] = *(const uint4*)kp; kreg[1] = *(const uint4*)(kp + 8);
        vreg[0] = *(const uint4*)vp; vreg[1] = *(const uint4*)(vp + 8);
    }

    for (int kt = 0; kt < 64; kt++) {
        __syncthreads();   // previous iteration's LDS reads done
        *(uint4*)&Ks[srow][scol] = kreg[0];
        *(uint4*)&Ks[srow][scol + 8] = kreg[1];
        {
            union { uint4 u; f16 h[8]; } va, vb;
            va.u = vreg[0]; vb.u = vreg[1];
#pragma unroll
            for (int j = 0; j < 8; j++) {
                Vts[scol + j][srow] = va.h[j];
                Vts[scol + 8 + j][srow] = vb.h[j];
            }
        }
        __syncthreads();
        if (kt + 1 < 64) {
            const f16* kp = qkv + (size_t)((kt + 1) * 64 + srow) * 768 + 256 + hq + scol;
            const f16* vp = qkv + (size_t)((kt + 1) * 64 + srow) * 768 + 512 + hq + scol;
            kreg[0] = *(const uint4*)kp; kreg[1] = *(const uint4*)(kp + 8);
            vreg[0] = *(const uint4*)vp; vreg[1] = *(const uint4*)(vp + 8);
        }

        // S = (Q @ K^T) * 0.125 ; C-layout: col(kv)=ln, row=quad*4+i
        f32x4 accS[4];
#pragma unroll
        for (int nt = 0; nt < 4; nt++) {
            union { f16x8 f; uint4 u; } b0, b1;
            b0.u = *(const uint4*)&Ks[nt * 16 + ln][quad * 8];
            b1.u = *(const uint4*)&Ks[nt * 16 + ln][32 + quad * 8];
            f32x4 a = {0.f, 0.f, 0.f, 0.f};
            a = __builtin_amdgcn_mfma_f32_16x16x32_f16(qfrag[0], b0.f, a, 0, 0, 0);
            a = __builtin_amdgcn_mfma_f32_16x16x32_f16(qfrag[1], b1.f, a, 0, 0, 0);
            accS[nt] = a;
        }
#pragma unroll
        for (int nt = 0; nt < 4; nt++)
#pragma unroll
            for (int i = 0; i < 4; i++) accS[nt][i] *= 0.125f;

        // online softmax per row (rows replicated across the 16 lanes of each quad-group)
        float mnew[4], alpha[4], rs[4];
#pragma unroll
        for (int i = 0; i < 4; i++) {
            float mx = fmaxf(fmaxf(accS[0][i], accS[1][i]), fmaxf(accS[2][i], accS[3][i]));
            mx = fmaxf(mx, __shfl_xor(mx, 1));
            mx = fmaxf(mx, __shfl_xor(mx, 2));
            mx = fmaxf(mx, __shfl_xor(mx, 4));
            mx = fmaxf(mx, __shfl_xor(mx, 8));
            mnew[i] = fmaxf(m_run[i], mx);
            rs[i] = 0.0f;
        }
#pragma unroll
        for (int nt = 0; nt < 4; nt++)
#pragma unroll
            for (int i = 0; i < 4; i++) {
                float p = __expf(accS[nt][i] - mnew[i]);
                accS[nt][i] = p;
                rs[i] += p;
            }
#pragma unroll
        for (int i = 0; i < 4; i++) {
            float s = rs[i];
            s += __shfl_xor(s, 1);
            s += __shfl_xor(s, 2);
            s += __shfl_xor(s, 4);
            s += __shfl_xor(s, 8);
            alpha[i] = __expf(m_run[i] - mnew[i]);
            l_run[i] = l_run[i] * alpha[i] + s;
            m_run[i] = mnew[i];
        }
#pragma unroll
        for (int dt = 0; dt < 4; dt++)
#pragma unroll
            for (int i = 0; i < 4; i++) Oacc[dt][i] *= alpha[i];

        // P -> LDS (C-layout scatter), then read back as A-operand (same wave: DS in-order)
#pragma unroll
        for (int nt = 0; nt < 4; nt++)
#pragma unroll
            for (int i = 0; i < 4; i++)
                Ps[w][quad * 4 + i][nt * 16 + ln] = (f16)accS[nt][i];

        union { f16x8 f; uint4 u; } pf0, pf1;
        pf0.u = *(const uint4*)&Ps[w][ln][quad * 8];
        pf1.u = *(const uint4*)&Ps[w][ln][32 + quad * 8];
#pragma unroll
        for (int dt = 0; dt < 4; dt++) {
            union { f16x8 f; uint4 u; } b0, b1;
            b0.u = *(const uint4*)&Vts[dt * 16 + ln][quad * 8];
            b1.u = *(const uint4*)&Vts[dt * 16 + ln][32 + quad * 8];
            Oacc[dt] = __builtin_amdgcn_mfma_f32_16x16x32_f16(pf0.f, b0.f, Oacc[dt], 0, 0, 0);
            Oacc[dt] = __builtin_amdgcn_mfma_f32_16x16x32_f16(pf1.f, b1.f, Oacc[dt], 0, 0, 0);
        }
    }

    float inv[4];
#pragma unroll
    for (int i = 0; i < 4; i++) inv[i] = 1.0f / l_run[i];
#pragma unroll
    for (int dt = 0; dt < 4; dt++)
#pragma unroll
        for (int i = 0; i < 4; i++)
            ctxbf[(size_t)(q0 + w * 16 + quad * 4 + i) * 256 + hq + dt * 16 + ln] =
                (f16)(Oacc[dt][i] * inv[i]);
}

// ---------------- layernorm, dual fp32/f16 outputs ----------------
__global__ __launch_bounds__(256) void ln_k(const float* __restrict__ X,
                                            const float* __restrict__ R,
                                            const float* __restrict__ gam,
                                            const float* __restrict__ bet,
                                            float* __restrict__ Of, f16* __restrict__ Oh, int doGelu) {
    __shared__ float sm[4];
    int n = blockIdx.x, c = threadIdx.x;
    float x = X[(size_t)n * DMODEL + c];
    if (R) x += R[(size_t)n * DMODEL + c];
    float s = x;
    for (int off = 32; off; off >>= 1) s += __shfl_down(s, off);
    if ((c & 63) == 0) sm[c >> 6] = s;
    __syncthreads();
    float mean = (sm[0] + sm[1] + sm[2] + sm[3]) * (1.0f / DMODEL);
    float d = x - mean;
    float s2 = d * d;
    for (int off = 32; off; off >>= 1) s2 += __shfl_down(s2, off);
    __syncthreads();
    if ((c & 63) == 0) sm[c >> 6] = s2;
    __syncthreads();
    float var = (sm[0] + sm[1] + sm[2] + sm[3]) * (1.0f / DMODEL);
    float y = d * rsqrtf(var + 1e-5f) * gam[c] + bet[c];
    if (doGelu) y = gelu_exact(y);
    size_t idx = (size_t)n * DMODEL + c;
    if (Of) Of[idx] = y;
    if (Oh) Oh[idx] = (f16)y;
}

// ---------------- router: top-1 gate ----------------
__global__ __launch_bounds__(64) void router_k(const float* __restrict__ z2,
                                               const float* __restrict__ grad,
                                               const float* __restrict__ Wr,
                                               const float* __restrict__ br,
                                               float* __restrict__ gate) {
    int n = blockIdx.x, t = threadIdx.x;
    float p0 = 0, p1 = 0, p2 = 0, p3 = 0;
#pragma unroll
    for (int i = 0; i < 4; i++) {
        int d = t + i * 64;
        float zv = z2[(size_t)n * DMODEL + d];
        p0 = fmaf(zv, Wr[d * 4 + 0], p0);
        p1 = fmaf(zv, Wr[d * 4 + 1], p1);
        p2 = fmaf(zv, Wr[d * 4 + 2], p2);
        p3 = fmaf(zv, Wr[d * 4 + 3], p3);
    }
    for (int off = 32; off; off >>= 1) {
        p0 += __shfl_down(p0, off);
        p1 += __shfl_down(p1, off);
        p2 += __shfl_down(p2, off);
        p3 += __shfl_down(p3, off);
    }
    if (t == 0) {
        float gv = grad[n];
        float l[4];
        l[0] = p0 + gv * Wr[256 * 4 + 0] + br[0];
        l[1] = p1 + gv * Wr[256 * 4 + 1] + br[1];
        l[2] = p2 + gv * Wr[256 * 4 + 2] + br[2];
        l[3] = p3 + gv * Wr[256 * 4 + 3] + br[3];
        float mx = fmaxf(fmaxf(l[0], l[1]), fmaxf(l[2], l[3]));
        float e[4], s = 0;
#pragma unroll
        for (int i = 0; i < 4; i++) { e[i] = __expf(l[i] - mx); s += e[i]; }
        int am = 0;
        float best = l[0];
#pragma unroll
        for (int i = 1; i < 4; i++)
            if (l[i] > best) { best = l[i]; am = i; }
        float p = e[am] / s;
#pragma unroll
        for (int i = 0; i < 4; i++) gate[(size_t)n * 4 + i] = (i == am) ? p : 0.0f;
    }
}

// ---------------- MoE gated combine: z3bf = f16(z2 + sum_e gate_e * (y_e + b2_e)) ----------------
__global__ __launch_bounds__(256) void moecomb_k(const float* __restrict__ ybuf,
                                                 const float* __restrict__ b2e,
                                                 const float* __restrict__ gate,
                                                 const float* __restrict__ z2,
                                                 f16* __restrict__ z3bf) {
    int i = (blockIdx.x * 256 + threadIdx.x) * 4;
    int row = i >> 8, c = i & 255;
    float4 acc = *(const float4*)(z2 + i);
#pragma unroll
    for (int e = 0; e < 4; e++) {
        float g = gate[row * 4 + e];
        if (g != 0.0f) {
            float4 y = *(const float4*)(ybuf + (size_t)e * (NTOK * DMODEL) + i);
            float4 b = *(const float4*)(b2e + e * 256 + c);
            acc.x += g * (y.x + b.x); acc.y += g * (y.y + b.y);
            acc.z += g * (y.z + b.z); acc.w += g * (y.w + b.w);
        }
    }
    union { ushort4 u; f16 h[4]; } o;
    o.h[0] = (f16)acc.x; o.h[1] = (f16)acc.y; o.h[2] = (f16)acc.z; o.h[3] = (f16)acc.w;
    *(ushort4*)(z3bf + i) = o.u;
}

// ---------------- functional head final ----------------
__global__ __launch_bounds__(256) void ghead_k(const f16* __restrict__ f,
                                               const float* __restrict__ Wf2,
                                               const float* __restrict__ bf2,
                                               float* __restrict__ out) {
    int n = blockIdx.x * 256 + threadIdx.x;
    float s = bf2[0];
#pragma unroll
    for (int c = 0; c < 8; c++) {
        union { uint4 u; f16 h[8]; } t;
        t.u = *(const uint4*)(f + (size_t)n * 64 + c * 8);
#pragma unroll
        for (int j = 0; j < 8; j++) s = fmaf((float)t.h[j], Wf2[c * 8 + j], s);
    }
    out[n] = 1.0f / (1.0f + expf(-s));
}

// ---------------- launch ----------------
extern "C" void kernel_launch(void* const* d_in, const int* in_sizes, int n_in,
                              void* d_out, int out_size, void* d_ws, size_t ws_size,
                              hipStream_t stream) {
    const float* vis   = (const float*)d_in[0];
    const float* pos   = (const float*)d_in[1];
    const float* grad  = (const float*)d_in[2];
    const float* Bf    = (const float*)d_in[3];
    const float* W_img = (const float*)d_in[4];
    const float* b_img = (const float*)d_in[5];
    const float* W_pos = (const float*)d_in[6];
    const float* b_pos = (const float*)d_in[7];
    const float* Wq = (const float*)d_in[8];  const float* bq = (const float*)d_in[9];
    const float* Wk = (const float*)d_in[10]; const float* bk = (const float*)d_in[11];
    const float* Wv = (const float*)d_in[12]; const float* bv = (const float*)d_in[13];
    const float* Wo = (const float*)d_in[14]; const float* bo = (const float*)d_in[15];
    const float* ln1g = (const float*)d_in[16]; const float* ln1b = (const float*)d_in[17];
    const float* Wr = (const float*)d_in[18]; const float* br = (const float*)d_in[19];
    const float* W1e = (const float*)d_in[20]; const float* b1e = (const float*)d_in[21];
    const float* W2e = (const float*)d_in[22]; const float* b2e = (const float*)d_in[23];
    const float* Wg1 = (const float*)d_in[24]; const float* bg1 = (const float*)d_in[25];
    const float* lngg = (const float*)d_in[26]; const float* lngb = (const float*)d_in[27];
    const float* Wg2 = (const float*)d_in[28]; const float* bg2 = (const float*)d_in[29];
    const float* Wf1 = (const float*)d_in[30]; const float* bf1 = (const float*)d_in[31];
    const float* Wf2 = (const float*)d_in[32]; const float* bf2 = (const float*)d_in[33];

    float* out = (float*)d_out;
    float* outMu = out;
    float* outTh = out + (size_t)NTOK * G_GENES;
    float* outG  = out + (size_t)2 * NTOK * G_GENES;

    // ---- workspace layout ----
    char* base = (char*)d_ws;
    size_t off = 0;
    auto A8 = [&](size_t bytes) { char* p = base + off; off += (bytes + 255) & ~(size_t)255; return p; };

    // region1 (16 MB): Abig (encoder A, 9.4MB) -> later ybuf (MoE expert outputs, 16MB)
    char* reg1 = A8(16 * 1024 * 1024);
    f16*   Abig = (f16*)reg1;
    float* ybuf = (float*)reg1;
    // region2 (32 MB): qkvbf (6.3MB, dead after flash) -> hbf (MoE hidden, 32MB)
    char* reg2 = A8(32 * 1024 * 1024);
    f16* qkvbf = (f16*)reg2;
    f16* hbf   = (f16*)reg2;

    f16* WtEnc = (f16*)A8((size_t)256 * 1152 * 2);
    f16* Wqkvt = (f16*)A8((size_t)768 * 256 * 2);
    f16* Wot   = (f16*)A8((size_t)256 * 256 * 2);
    f16* W1t   = (f16*)A8((size_t)4 * 1024 * 256 * 2);
    f16* W2t   = (f16*)A8((size_t)4 * 256 * 1024 * 2);
    f16* Wg1t  = (f16*)A8((size_t)256 * 256 * 2);
    f16* Wg2t  = (f16*)A8((size_t)4000 * 256 * 2);
    f16* Wf1t  = (f16*)A8((size_t)64 * 256 * 2);
    float* benc    = (float*)A8(256 * 4);
    float* biasqkv = (float*)A8(768 * 4);
    float* z    = (float*)A8((size_t)NTOK * DMODEL * 4);
    float* z2   = (float*)A8((size_t)NTOK * DMODEL * 4);
    float* attn = (float*)A8((size_t)NTOK * DMODEL * 4);
    float* tbuf = (float*)A8((size_t)NTOK * DMODEL * 4);
    f16* zbf    = (f16*)A8((size_t)NTOK * DMODEL * 2);
    f16* z2bf   = (f16*)A8((size_t)NTOK * DMODEL * 2);
    f16* z3bf   = (f16*)A8((size_t)NTOK * DMODEL * 2);
    f16* ctxbf  = (f16*)A8((size_t)NTOK * DMODEL * 2);
    f16* dbufbf = (f16*)A8((size_t)NTOK * DMODEL * 2);
    f16* fbf    = (f16*)A8((size_t)NTOK * 64 * 2);
    float* gate = (float*)A8((size_t)NTOK * 4 * 4);

    dim3 blk(256);

    // ---- weight prep ----
    TDs td;
    int nd = 0;
    auto addT = [&](const float* s, f16* d, int R, int C, int ldo) { td.t[nd++] = TD{s, d, R, C, ldo}; };
    addT(W_img, WtEnc, 1024, 256, 1152);
    addT(W_pos, WtEnc + 1024, 128, 256, 1152);
    addT(Wq, Wqkvt, 256, 256, 256);
    addT(Wk, Wqkvt + 256 * 256, 256, 256, 256);
    addT(Wv, Wqkvt + 512 * 256, 256, 256, 256);
    addT(Wo, Wot, 256, 256, 256);
    for (int e = 0; e < 4; e++) addT(W1e + (size_t)e * 262144, W1t + (size_t)e * 262144, 256, 1024, 256);
    for (int e = 0; e < 4; e++) addT(W2e + (size_t)e * 262144, W2t + (size_t)e * 262144, 1024, 256, 1024);
    addT(Wg1, Wg1t, 256, 256, 256);
    addT(Wg2, Wg2t, 256, 4000, 256);
    addT(Wf1, Wf1t, 256, 64, 256);
    tconv_k<<<dim3(32, 125, 17), blk, 0, stream>>>(td);
    addbias_k<<<1, blk, 0, stream>>>(b_img, b_pos, benc);
    hipMemcpyAsync(biasqkv, bq, 256 * 4, hipMemcpyDeviceToDevice, stream);
    hipMemcpyAsync(biasqkv + 256, bk, 256 * 4, hipMemcpyDeviceToDevice, stream);
    hipMemcpyAsync(biasqkv + 512, bv, 256 * 4, hipMemcpyDeviceToDevice, stream);

    // ---- encoder ----
    cvt_vis_k<<<NTOK, blk, 0, stream>>>(vis, Abig);
    fourier_k<<<NTOK, 64, 0, stream>>>(pos, Bf, Abig);
    bgemm_k<2, EPI_DUAL, 0><<<dim3(32, 4, 1), blk, 0, stream>>>(
        Abig, 1152, WtEnc, 1152, benc, z, zbf, 256, NTOK, 256, 1152, 0, 0, 0, 0, nullptr, nullptr);

    // ---- fused QKV ----
    bgemm_k<4, EPI_F16, 0><<<dim3(32, 6, 1), blk, 0, stream>>>(
        zbf, 256, Wqkvt, 256, biasqkv, nullptr, qkvbf, 768, NTOK, 768, 256, 0, 0, 0, 0, nullptr, nullptr);

    // ---- flash attention ----
    flash_k<<<dim3(64, 4, 1), blk, 0, stream>>>(qkvbf, ctxbf);
    bgemm_k<2, EPI_F32, 0><<<dim3(32, 4, 1), blk, 0, stream>>>(
        ctxbf, 256, Wot, 256, bo, attn, nullptr, 256, NTOK, 256, 256, 0, 0, 0, 0, nullptr, nullptr);
    ln_k<<<NTOK, blk, 0, stream>>>(z, attn, ln1g, ln1b, z2, z2bf, 0);

    // ---- MoE (dense over 4 experts, batched launches) ----
    router_k<<<NTOK, 64, 0, stream>>>(z2, grad, Wr, br, gate);
    bgemm_k<4, EPI_GELU_F16, 1><<<dim3(32, 8, 4), blk, 0, stream>>>(
        z2bf, 256, W1t, 256, b1e, nullptr, hbf, 1024, NTOK, 1024, 256,
        0, 262144, 1024, (size_t)NTOK * 1024, nullptr, nullptr);
    bgemm_k<4, EPI_F32, 1><<<dim3(32, 2, 4), blk, 0, stream>>>(
        hbf, 1024, W2t, 1024, nullptr, ybuf, nullptr, 256, NTOK, 256, 1024,
        (size_t)NTOK * 1024, 262144, 0, (size_t)NTOK * 256, nullptr, nullptr);
    moecomb_k<<<1024, blk, 0, stream>>>(ybuf, b2e, gate, z2, z3bf);

    // ---- gene decoder ----
    bgemm_k<2, EPI_F32, 0><<<dim3(32, 4, 1), blk, 0, stream>>>(
        z3bf, 256, Wg1t, 256, bg1, tbuf, nullptr, 256, NTOK, 256, 256, 0, 0, 0, 0, nullptr, nullptr);
    ln_k<<<NTOK, blk, 0, stream>>>(tbuf, nullptr, lngg, lngb, nullptr, dbufbf, 1);
    bgemm_k<4, EPI_GENE, 0><<<dim3(32, 32, 1), blk, 0, stream>>>(
        dbufbf, 256, Wg2t, 256, bg2, nullptr, nullptr, 4000, NTOK, 4000, 256, 0, 0, 0, 0, outMu, outTh);

    // ---- functional head ----
    bgemm_k<2, EPI_GELU_F16, 0><<<dim3(32, 1, 1), blk, 0, stream>>>(
        z3bf, 256, Wf1t, 256, bf1, nullptr, fbf, 64, NTOK, 64, 256, 0, 0, 0, 0, nullptr, nullptr);
    ghead_k<<<NTOK / 256, blk, 0, stream>>>(fbf, Wf2, bf2, outG);
}

// Round 4
// 454.889 us; speedup vs baseline: 3.5587x; 1.2779x over previous
//
#include <hip/hip_runtime.h>
#include <math.h>

#define NTOK 4096
#define DMODEL 256
#define G_GENES 2000

typedef _Float16 f16;
typedef _Float16 f16x8 __attribute__((ext_vector_type(8)));
typedef float f32x4 __attribute__((ext_vector_type(4)));

// ---------------- helpers ----------------
__device__ __forceinline__ float gelu_exact(float x) {
    return 0.5f * x * (1.0f + erff(x * 0.70710678118654752f));
}
__device__ __forceinline__ float softplus_fast(float x) {
    return fmaxf(x, 0.0f) + __logf(1.0f + __expf(-fabsf(x)));
}

// ---------------- fourier encoding (writes f16 into Abig cols 1024..1151) ----------------
__global__ __launch_bounds__(64) void fourier_k(const float* __restrict__ pos,
                                                const float* __restrict__ B,
                                                f16* __restrict__ Abig) {
    int n = blockIdx.x, m = threadIdx.x;
    float xp = 6.283185307179586f *
               (pos[n * 3 + 0] * B[m] + pos[n * 3 + 1] * B[64 + m] + pos[n * 3 + 2] * B[128 + m]);
    Abig[(size_t)n * 1152 + 1024 + m] = (f16)sinf(xp);
    Abig[(size_t)n * 1152 + 1088 + m] = (f16)cosf(xp);
}

// ---------------- vis f32 -> f16 strided into Abig cols 0..1023 ----------------
__global__ __launch_bounds__(256) void cvt_vis_k(const float* __restrict__ vis, f16* __restrict__ Abig) {
    int n = blockIdx.x, t = threadIdx.x;
    float4 v = *(const float4*)(vis + (size_t)n * 1024 + t * 4);
    union { ushort4 u; f16 h[4]; } o;
    o.h[0] = (f16)v.x; o.h[1] = (f16)v.y; o.h[2] = (f16)v.z; o.h[3] = (f16)v.w;
    *(ushort4*)(Abig + (size_t)n * 1152 + t * 4) = o.u;
}

// ---------------- batched transpose-convert, flat tile list ----------------
// all R,C multiples of 32
struct TD { const float* s; f16* d; int R, C; int ldo; };
struct TDs { TD t[17]; int pre[18]; };
__global__ __launch_bounds__(256) void tconv_k(TDs ds) {
    int bid = blockIdx.x;
    int ti = 0;
#pragma unroll
    for (int i = 0; i < 17; i++)
        if (bid >= ds.pre[i + 1]) ti = i + 1;
    TD td = ds.t[ti];
    int local = bid - ds.pre[ti];
    int yt = td.C >> 5;
    int r0 = (local / yt) << 5;
    int c0 = (local % yt) << 5;
    __shared__ float tile[32][33];
    int tx = threadIdx.x & 31, ty = threadIdx.x >> 5;
#pragma unroll
    for (int i = 0; i < 32; i += 8)
        tile[ty + i][tx] = td.s[(size_t)(r0 + ty + i) * td.C + c0 + tx];
    __syncthreads();
#pragma unroll
    for (int i = 0; i < 32; i += 8)
        td.d[(size_t)(c0 + ty + i) * td.ldo + r0 + tx] = (f16)tile[tx][ty + i];
}

// ---------------- f16 transpose (V^T from qkv buffer) ----------------
__global__ __launch_bounds__(256) void tconvh_k(const f16* __restrict__ src, int ldin,
                                                f16* __restrict__ dst, int ldo) {
    __shared__ f16 tile[32][33];
    int r0 = blockIdx.x * 32, c0 = blockIdx.y * 32;
    int tx = threadIdx.x & 31, ty = threadIdx.x >> 5;
#pragma unroll
    for (int i = 0; i < 32; i += 8)
        tile[ty + i][tx] = src[(size_t)(r0 + ty + i) * ldin + c0 + tx];
    __syncthreads();
#pragma unroll
    for (int i = 0; i < 32; i += 8)
        dst[(size_t)(c0 + ty + i) * ldo + r0 + tx] = tile[tx][ty + i];
}

// ---------------- bias sum ----------------
__global__ __launch_bounds__(256) void addbias_k(const float* a, const float* b, float* o) {
    int t = threadIdx.x;
    o[t] = a[t] + b[t];
}

// ---------------- MFMA f16 GEMM ----------------
// C[*,Ncols] = epi(A[*,K](f16) @ B^T + bias), B as [Ncols, K] f16.
// BM=128, BN=MTN*32, BK=64; 256 threads = 4 waves 2x2; wave tile 64 x (MTN*16).
// MODE 0: plain. MODE 1: MoE-up (expert via temap[bx], A rows gathered via gidx).
// MODE 2: MoE-down (expert via temap[bx], epilogue scatters z3bf = z2 + gval*(v+bias)).
#define EPI_F32 0
#define EPI_DUAL 1
#define EPI_F16 2
#define EPI_GELU_F16 3
#define EPI_GENE 4
#define EPI_MOESC 5

template <int MTN, int EPI, int MODE>
__global__ __launch_bounds__(256) void bgemm_k(
    const f16* __restrict__ A, int lda,
    const f16* __restrict__ B, int ldb,
    const float* __restrict__ bias,
    float* __restrict__ Cf, f16* __restrict__ Ch, int ldc,
    int Ncols, int K,
    size_t eB, size_t eBias,
    const int* __restrict__ gidx, const int* __restrict__ temap,
    const float* __restrict__ z2, const float* __restrict__ gval,
    float* __restrict__ outMu, float* __restrict__ outTheta) {
    constexpr int BN = MTN * 32;
    __shared__ __align__(16) char smem[(128 + BN) * 72 * 2];
    f16 (*As)[72] = (f16(*)[72])smem;
    f16 (*Bs)[72] = (f16(*)[72])(smem + (size_t)128 * 72 * 2);

    const int tid = threadIdx.x;
    const int m0 = blockIdx.x * 128;
    const int n0 = blockIdx.y * BN;
    const int w = tid >> 6, lane = tid & 63;
    const int wr = w >> 1, wc = w & 1;
    const int ln = lane & 15, lg = lane >> 4;
    const int sr = tid >> 3;        // 0..31
    const int sc = (tid & 7) * 8;   // f16 offset 0..56

    if (MODE == 1 || MODE == 2) {
        int e = temap[blockIdx.x];
        B += (size_t)e * eB;
        if (bias) bias += (size_t)e * eBias;
    }

    int grows[4];
#pragma unroll
    for (int i = 0; i < 4; i++) {
        int r = m0 + sr + i * 32;
        if (MODE == 1) {
            int g = gidx[r];
            grows[i] = (g < 0) ? 0 : g;
        } else {
            grows[i] = r;
        }
    }

    f32x4 acc[4][MTN];
    f32x4 zf = {0.f, 0.f, 0.f, 0.f};
#pragma unroll
    for (int i = 0; i < 4; i++)
#pragma unroll
        for (int j = 0; j < MTN; j++) acc[i][j] = zf;

    for (int k0 = 0; k0 < K; k0 += 64) {
#pragma unroll
        for (int i = 0; i < 4; i++) {
            uint4 v = *(const uint4*)(A + (size_t)grows[i] * lda + k0 + sc);
            int r = sr + i * 32;
            *(uint2*)&As[r][sc] = make_uint2(v.x, v.y);
            *(uint2*)&As[r][sc + 4] = make_uint2(v.z, v.w);
        }
#pragma unroll
        for (int i = 0; i < MTN; i++) {
            int r = sr + i * 32;
            uint4 v = make_uint4(0, 0, 0, 0);
            if (n0 + r < Ncols) v = *(const uint4*)(B + (size_t)(n0 + r) * ldb + k0 + sc);
            *(uint2*)&Bs[r][sc] = make_uint2(v.x, v.y);
            *(uint2*)&Bs[r][sc + 4] = make_uint2(v.z, v.w);
        }
        __syncthreads();
#pragma unroll
        for (int ks = 0; ks < 64; ks += 32) {
            f16x8 a[4], b[MTN];
#pragma unroll
            for (int t = 0; t < 4; t++) {
                const f16* p = &As[wr * 64 + t * 16 + ln][ks + lg * 8];
                union { f16x8 f; uint2 u[2]; } tmp;
                tmp.u[0] = *(const uint2*)p;
                tmp.u[1] = *(const uint2*)(p + 4);
                a[t] = tmp.f;
            }
#pragma unroll
            for (int t = 0; t < MTN; t++) {
                const f16* p = &Bs[wc * (MTN * 16) + t * 16 + ln][ks + lg * 8];
                union { f16x8 f; uint2 u[2]; } tmp;
                tmp.u[0] = *(const uint2*)p;
                tmp.u[1] = *(const uint2*)(p + 4);
                b[t] = tmp.f;
            }
#pragma unroll
            for (int tm = 0; tm < 4; tm++)
#pragma unroll
                for (int tn = 0; tn < MTN; tn++)
                    acc[tm][tn] = __builtin_amdgcn_mfma_f32_16x16x32_f16(a[tm], b[tn], acc[tm][tn], 0, 0, 0);
        }
        __syncthreads();
    }

    if (EPI == EPI_GENE) {
        float bval[MTN];
#pragma unroll
        for (int tn = 0; tn < MTN; tn++) {
            int col = n0 + wc * (MTN * 16) + tn * 16 + ln;
            bval[tn] = (col < Ncols) ? bias[col] : 0.0f;
        }
        float* Cs = (float*)smem;   // 32 x 132 f32 = 16.5 KB
        const int rrow = tid >> 3;
        const int rseg = tid & 7;
#pragma unroll
        for (int tm = 0; tm < 4; tm++) {
            __syncthreads();
#pragma unroll
            for (int tn = 0; tn < MTN; tn++) {
                int lc = wc * (MTN * 16) + tn * 16 + ln;
#pragma unroll
                for (int i = 0; i < 4; i++) {
                    int lr = wr * 16 + lg * 4 + i;
                    Cs[lr * 132 + lc] = acc[tm][tn][i] + bval[tn];
                }
            }
            __syncthreads();
            int grow = m0 + ((rrow >> 4) * 64) + tm * 16 + (rrow & 15);
            const float* cr = &Cs[rrow * 132 + rseg * 16];
            float mu[8], th[8];
#pragma unroll
            for (int g = 0; g < 8; g++) {
                mu[g] = softplus_fast(cr[2 * g]);
                th[g] = softplus_fast(cr[2 * g + 1]) + 1e-6f;
            }
            int gbase = (n0 + rseg * 16) >> 1;
            float* mp = outMu + (size_t)grow * G_GENES + gbase;
            float* tp = outTheta + (size_t)grow * G_GENES + gbase;
            if (gbase + 8 <= G_GENES) {
                *(float4*)mp = make_float4(mu[0], mu[1], mu[2], mu[3]);
                *(float4*)(mp + 4) = make_float4(mu[4], mu[5], mu[6], mu[7]);
                *(float4*)tp = make_float4(th[0], th[1], th[2], th[3]);
                *(float4*)(tp + 4) = make_float4(th[4], th[5], th[6], th[7]);
            } else {
#pragma unroll
                for (int g = 0; g < 8; g++)
                    if (gbase + g < G_GENES) { mp[g] = mu[g]; tp[g] = th[g]; }
            }
        }
        return;
    }

#pragma unroll
    for (int tm = 0; tm < 4; tm++) {
#pragma unroll
        for (int tn = 0; tn < MTN; tn++) {
            int col = n0 + wc * (MTN * 16) + tn * 16 + ln;
            if (col >= Ncols) continue;
#pragma unroll
            for (int i = 0; i < 4; i++) {
                int row = m0 + wr * 64 + tm * 16 + lg * 4 + i;
                float v = acc[tm][tn][i];
                if (EPI == EPI_MOESC) {
                    int tok = gidx[row];
                    if (tok < 0) continue;
                    v += bias[col];
                    size_t oi = (size_t)tok * ldc + col;
                    Ch[oi] = (f16)(z2[oi] + gval[tok] * v);
                    continue;
                }
                size_t idx = (size_t)row * ldc + col;
                if (EPI == EPI_F32) {
                    if (bias) v += bias[col];
                    Cf[idx] = v;
                } else if (EPI == EPI_DUAL) {
                    v += bias[col];
                    Cf[idx] = v;
                    Ch[idx] = (f16)v;
                } else if (EPI == EPI_F16) {
                    v += bias[col];
                    Ch[idx] = (f16)v;
                } else if (EPI == EPI_GELU_F16) {
                    v += bias[col];
                    Ch[idx] = (f16)gelu_exact(v);
                }
            }
        }
    }
}

// ---------------- flash attention, split-KV ----------------
// grid (64 q-tiles, 4 heads, 4 kv-splits), 256 threads = 4 waves; wave owns 16 Q rows.
// Writes unnormalized O partials + (m,l) per split.
__global__ __launch_bounds__(256) void flash_k(const f16* __restrict__ qkv,
                                               const f16* __restrict__ Vt,
                                               float* __restrict__ Opart,
                                               float2* __restrict__ mlpart) {
    __shared__ f16 Ks[64][72];
    __shared__ f16 Vts[64][72];     // [d][kv]
    __shared__ f16 Ps[4][16][72];
    const int tid = threadIdx.x;
    const int w = tid >> 6, lane = tid & 63;
    const int ln = lane & 15, quad = lane >> 4;
    const int q0 = blockIdx.x * 64;
    const int hq = blockIdx.y * 64;
    const int kt0 = blockIdx.z * 16;

    f16x8 qfrag[2];
    {
        const f16* qp = qkv + (size_t)(q0 + w * 16 + ln) * 768 + hq + quad * 8;
        union { f16x8 f; uint4 u; } t0, t1;
        t0.u = *(const uint4*)qp;
        t1.u = *(const uint4*)(qp + 32);
        qfrag[0] = t0.f; qfrag[1] = t1.f;
    }

    const int srow = tid >> 2;        // 0..63
    const int scol = (tid & 3) * 16;  // 0,16,32,48

    float m_run[4], l_run[4];
    f32x4 Oacc[4];
#pragma unroll
    for (int i = 0; i < 4; i++) {
        m_run[i] = -1e30f; l_run[i] = 0.0f;
        Oacc[i] = (f32x4){0.f, 0.f, 0.f, 0.f};
    }

    uint4 kreg[2], vreg[2];
    {
        const f16* kp = qkv + (size_t)(kt0 * 64 + srow) * 768 + 256 + hq + scol;
        const f16* vp = Vt + (size_t)(hq + srow) * 4096 + kt0 * 64 + scol;
        kreg[0] = *(const uint4*)kp; kreg[1] = *(const uint4*)(kp + 8);
        vreg[0] = *(const uint4*)vp; vreg[1] = *(const uint4*)(vp + 8);
    }

    for (int kt = kt0; kt < kt0 + 16; kt++) {
        __syncthreads();
        *(uint4*)&Ks[srow][scol] = kreg[0];
        *(uint4*)&Ks[srow][scol + 8] = kreg[1];
        *(uint4*)&Vts[srow][scol] = vreg[0];
        *(uint4*)&Vts[srow][scol + 8] = vreg[1];
        __syncthreads();
        if (kt + 1 < kt0 + 16) {
            const f16* kp = qkv + (size_t)((kt + 1) * 64 + srow) * 768 + 256 + hq + scol;
            const f16* vp = Vt + (size_t)(hq + srow) * 4096 + (kt + 1) * 64 + scol;
            kreg[0] = *(const uint4*)kp; kreg[1] = *(const uint4*)(kp + 8);
            vreg[0] = *(const uint4*)vp; vreg[1] = *(const uint4*)(vp + 8);
        }

        // S = (Q K^T)/8 ; C-layout: col(kv)=ln, row=quad*4+i
        f32x4 accS[4];
#pragma unroll
        for (int nt = 0; nt < 4; nt++) {
            union { f16x8 f; uint4 u; } b0, b1;
            b0.u = *(const uint4*)&Ks[nt * 16 + ln][quad * 8];
            b1.u = *(const uint4*)&Ks[nt * 16 + ln][32 + quad * 8];
            f32x4 a = {0.f, 0.f, 0.f, 0.f};
            a = __builtin_amdgcn_mfma_f32_16x16x32_f16(qfrag[0], b0.f, a, 0, 0, 0);
            a = __builtin_amdgcn_mfma_f32_16x16x32_f16(qfrag[1], b1.f, a, 0, 0, 0);
            accS[nt] = a;
        }
#pragma unroll
        for (int nt = 0; nt < 4; nt++)
#pragma unroll
            for (int i = 0; i < 4; i++) accS[nt][i] *= 0.125f;

        float mnew[4], alpha[4], rs[4];
#pragma unroll
        for (int i = 0; i < 4; i++) {
            float mx = fmaxf(fmaxf(accS[0][i], accS[1][i]), fmaxf(accS[2][i], accS[3][i]));
            mx = fmaxf(mx, __shfl_xor(mx, 1));
            mx = fmaxf(mx, __shfl_xor(mx, 2));
            mx = fmaxf(mx, __shfl_xor(mx, 4));
            mx = fmaxf(mx, __shfl_xor(mx, 8));
            mnew[i] = fmaxf(m_run[i], mx);
            rs[i] = 0.0f;
        }
#pragma unroll
        for (int nt = 0; nt < 4; nt++)
#pragma unroll
            for (int i = 0; i < 4; i++) {
                float p = __expf(accS[nt][i] - mnew[i]);
                accS[nt][i] = p;
                rs[i] += p;
            }
#pragma unroll
        for (int i = 0; i < 4; i++) {
            float s = rs[i];
            s += __shfl_xor(s, 1);
            s += __shfl_xor(s, 2);
            s += __shfl_xor(s, 4);
            s += __shfl_xor(s, 8);
            alpha[i] = __expf(m_run[i] - mnew[i]);
            l_run[i] = l_run[i] * alpha[i] + s;
            m_run[i] = mnew[i];
        }
#pragma unroll
        for (int dt = 0; dt < 4; dt++)
#pragma unroll
            for (int i = 0; i < 4; i++) Oacc[dt][i] *= alpha[i];

#pragma unroll
        for (int nt = 0; nt < 4; nt++)
#pragma unroll
            for (int i = 0; i < 4; i++)
                Ps[w][quad * 4 + i][nt * 16 + ln] = (f16)accS[nt][i];

        union { f16x8 f; uint4 u; } pf0, pf1;
        pf0.u = *(const uint4*)&Ps[w][ln][quad * 8];
        pf1.u = *(const uint4*)&Ps[w][ln][32 + quad * 8];
#pragma unroll
        for (int dt = 0; dt < 4; dt++) {
            union { f16x8 f; uint4 u; } b0, b1;
            b0.u = *(const uint4*)&Vts[dt * 16 + ln][quad * 8];
            b1.u = *(const uint4*)&Vts[dt * 16 + ln][32 + quad * 8];
            Oacc[dt] = __builtin_amdgcn_mfma_f32_16x16x32_f16(pf0.f, b0.f, Oacc[dt], 0, 0, 0);
            Oacc[dt] = __builtin_amdgcn_mfma_f32_16x16x32_f16(pf1.f, b1.f, Oacc[dt], 0, 0, 0);
        }
    }

    const int s = blockIdx.z;
#pragma unroll
    for (int dt = 0; dt < 4; dt++)
#pragma unroll
        for (int i = 0; i < 4; i++)
            Opart[((size_t)(s * NTOK) + q0 + w * 16 + quad * 4 + i) * 256 + hq + dt * 16 + ln] =
                Oacc[dt][i];
    if (ln == 0) {
#pragma unroll
        for (int i = 0; i < 4; i++)
            mlpart[(size_t)(s * 4 + blockIdx.y) * NTOK + q0 + w * 16 + quad * 4 + i] =
                make_float2(m_run[i], l_run[i]);
    }
}

// ---------------- flash combine: ctx = (sum_s w_s O_s) / (sum_s w_s l_s) ----------------
__global__ __launch_bounds__(256) void fcomb_k(const float* __restrict__ Opart,
                                               const float2* __restrict__ mlpart,
                                               f16* __restrict__ ctxbf) {
    int t = blockIdx.x * 256 + threadIdx.x;   // over 4096*4*16
    int n = t >> 6;
    int rem = t & 63;
    int h = rem >> 4;
    int d4 = (rem & 15) * 4;
    float2 ml[4];
    float mmax = -1e30f;
#pragma unroll
    for (int s = 0; s < 4; s++) {
        ml[s] = mlpart[(size_t)(s * 4 + h) * NTOK + n];
        mmax = fmaxf(mmax, ml[s].x);
    }
    float wgt[4], l = 0.0f;
#pragma unroll
    for (int s = 0; s < 4; s++) {
        wgt[s] = __expf(ml[s].x - mmax);
        l += wgt[s] * ml[s].y;
    }
    float4 o = {0.f, 0.f, 0.f, 0.f};
#pragma unroll
    for (int s = 0; s < 4; s++) {
        float4 p = *(const float4*)(Opart + ((size_t)(s * NTOK) + n) * 256 + h * 64 + d4);
        o.x += wgt[s] * p.x; o.y += wgt[s] * p.y;
        o.z += wgt[s] * p.z; o.w += wgt[s] * p.w;
    }
    float inv = 1.0f / l;
    union { ushort4 u; f16 hh[4]; } pk;
    pk.hh[0] = (f16)(o.x * inv); pk.hh[1] = (f16)(o.y * inv);
    pk.hh[2] = (f16)(o.z * inv); pk.hh[3] = (f16)(o.w * inv);
    *(ushort4*)(ctxbf + (size_t)n * 256 + h * 64 + d4) = pk.u;
}

// ---------------- layernorm, dual fp32/f16 outputs ----------------
__global__ __launch_bounds__(256) void ln_k(const float* __restrict__ X,
                                            const float* __restrict__ R,
                                            const float* __restrict__ gam,
                                            const float* __restrict__ bet,
                                            float* __restrict__ Of, f16* __restrict__ Oh, int doGelu) {
    __shared__ float sm[4];
    int n = blockIdx.x, c = threadIdx.x;
    float x = X[(size_t)n * DMODEL + c];
    if (R) x += R[(size_t)n * DMODEL + c];
    float s = x;
    for (int off = 32; off; off >>= 1) s += __shfl_down(s, off);
    if ((c & 63) == 0) sm[c >> 6] = s;
    __syncthreads();
    float mean = (sm[0] + sm[1] + sm[2] + sm[3]) * (1.0f / DMODEL);
    float d = x - mean;
    float s2 = d * d;
    for (int off = 32; off; off >>= 1) s2 += __shfl_down(s2, off);
    __syncthreads();
    if ((c & 63) == 0) sm[c >> 6] = s2;
    __syncthreads();
    float var = (sm[0] + sm[1] + sm[2] + sm[3]) * (1.0f / DMODEL);
    float y = d * rsqrtf(var + 1e-5f) * gam[c] + bet[c];
    if (doGelu) y = gelu_exact(y);
    size_t idx = (size_t)n * DMODEL + c;
    if (Of) Of[idx] = y;
    if (Oh) Oh[idx] = (f16)y;
}

// ---------------- router: top-1 expert id + gate value ----------------
__global__ __launch_bounds__(64) void router_k(const float* __restrict__ z2,
                                               const float* __restrict__ grad,
                                               const float* __restrict__ Wr,
                                               const float* __restrict__ br,
                                               int* __restrict__ eid,
                                               float* __restrict__ gval) {
    int n = blockIdx.x, t = threadIdx.x;
    float p0 = 0, p1 = 0, p2 = 0, p3 = 0;
#pragma unroll
    for (int i = 0; i < 4; i++) {
        int d = t + i * 64;
        float zv = z2[(size_t)n * DMODEL + d];
        p0 = fmaf(zv, Wr[d * 4 + 0], p0);
        p1 = fmaf(zv, Wr[d * 4 + 1], p1);
        p2 = fmaf(zv, Wr[d * 4 + 2], p2);
        p3 = fmaf(zv, Wr[d * 4 + 3], p3);
    }
    for (int off = 32; off; off >>= 1) {
        p0 += __shfl_down(p0, off);
        p1 += __shfl_down(p1, off);
        p2 += __shfl_down(p2, off);
        p3 += __shfl_down(p3, off);
    }
    if (t == 0) {
        float gv = grad[n];
        float l[4];
        l[0] = p0 + gv * Wr[256 * 4 + 0] + br[0];
        l[1] = p1 + gv * Wr[256 * 4 + 1] + br[1];
        l[2] = p2 + gv * Wr[256 * 4 + 2] + br[2];
        l[3] = p3 + gv * Wr[256 * 4 + 3] + br[3];
        float mx = fmaxf(fmaxf(l[0], l[1]), fmaxf(l[2], l[3]));
        float e[4], s = 0;
#pragma unroll
        for (int i = 0; i < 4; i++) { e[i] = __expf(l[i] - mx); s += e[i]; }
        int am = 0;
        float best = l[0];
#pragma unroll
        for (int i = 1; i < 4; i++)
            if (l[i] > best) { best = l[i]; am = i; }
        eid[n] = am;
        gval[n] = e[am] / s;
    }
}

// ---------------- MoE compaction: 128-aligned per-expert segments ----------------
__global__ __launch_bounds__(256) void compact_k(const int* __restrict__ eid,
                                                 int* __restrict__ gidx,
                                                 int* __restrict__ temap) {
    __shared__ int cnt[4], poff[4], cur[4];
    int t = threadIdx.x;
    if (t < 4) cnt[t] = 0;
    __syncthreads();
    for (int it = 0; it < 16; it++)
        atomicAdd(&cnt[eid[it * 256 + t]], 1);
    __syncthreads();
    if (t == 0) {
        int o = 0;
        for (int e = 0; e < 4; e++) {
            poff[e] = o;
            cur[e] = o;
            o += (cnt[e] + 127) & ~127;
        }
    }
    __syncthreads();
    if (t < 36) {
        int e = 0;
        for (int x = 0; x < 4; x++) {
            int seg0 = poff[x] >> 7;
            int seg1 = (poff[x] + ((cnt[x] + 127) & ~127)) >> 7;
            if (t >= seg0 && t < seg1) e = x;
        }
        temap[t] = e;
    }
    for (int i = t; i < 4608; i += 256) gidx[i] = -1;
    __syncthreads();
    for (int it = 0; it < 16; it++) {
        int n = it * 256 + t;
        int slot = atomicAdd(&cur[eid[n]], 1);
        gidx[slot] = n;
    }
}

// ---------------- functional head final ----------------
__global__ __launch_bounds__(256) void ghead_k(const f16* __restrict__ f,
                                               const float* __restrict__ Wf2,
                                               const float* __restrict__ bf2,
                                               float* __restrict__ out) {
    int n = blockIdx.x * 256 + threadIdx.x;
    float s = bf2[0];
#pragma unroll
    for (int c = 0; c < 8; c++) {
        union { uint4 u; f16 h[8]; } t;
        t.u = *(const uint4*)(f + (size_t)n * 64 + c * 8);
#pragma unroll
        for (int j = 0; j < 8; j++) s = fmaf((float)t.h[j], Wf2[c * 8 + j], s);
    }
    out[n] = 1.0f / (1.0f + expf(-s));
}

// ---------------- launch ----------------
extern "C" void kernel_launch(void* const* d_in, const int* in_sizes, int n_in,
                              void* d_out, int out_size, void* d_ws, size_t ws_size,
                              hipStream_t stream) {
    const float* vis   = (const float*)d_in[0];
    const float* pos   = (const float*)d_in[1];
    const float* grad  = (const float*)d_in[2];
    const float* Bf    = (const float*)d_in[3];
    const float* W_img = (const float*)d_in[4];
    const float* b_img = (const float*)d_in[5];
    const float* W_pos = (const float*)d_in[6];
    const float* b_pos = (const float*)d_in[7];
    const float* Wq = (const float*)d_in[8];  const float* bq = (const float*)d_in[9];
    const float* Wk = (const float*)d_in[10]; const float* bk = (const float*)d_in[11];
    const float* Wv = (const float*)d_in[12]; const float* bv = (const float*)d_in[13];
    const float* Wo = (const float*)d_in[14]; const float* bo = (const float*)d_in[15];
    const float* ln1g = (const float*)d_in[16]; const float* ln1b = (const float*)d_in[17];
    const float* Wr = (const float*)d_in[18]; const float* br = (const float*)d_in[19];
    const float* W1e = (const float*)d_in[20]; const float* b1e = (const float*)d_in[21];
    const float* W2e = (const float*)d_in[22]; const float* b2e = (const float*)d_in[23];
    const float* Wg1 = (const float*)d_in[24]; const float* bg1 = (const float*)d_in[25];
    const float* lngg = (const float*)d_in[26]; const float* lngb = (const float*)d_in[27];
    const float* Wg2 = (const float*)d_in[28]; const float* bg2 = (const float*)d_in[29];
    const float* Wf1 = (const float*)d_in[30]; const float* bf1 = (const float*)d_in[31];
    const float* Wf2 = (const float*)d_in[32]; const float* bf2 = (const float*)d_in[33];

    float* out = (float*)d_out;
    float* outMu = out;
    float* outTh = out + (size_t)NTOK * G_GENES;
    float* outG  = out + (size_t)2 * NTOK * G_GENES;

    // ---- workspace ----
    char* base = (char*)d_ws;
    size_t off = 0;
    auto A8 = [&](size_t bytes) { char* p = base + off; off += (bytes + 255) & ~(size_t)255; return p; };

    // region1 (16 MB): Abig (encoder A) -> Opart (flash partials)
    char* reg1 = A8(16 * 1024 * 1024);
    f16*   Abig  = (f16*)reg1;
    float* Opart = (float*)reg1;
    // region2 (20 MB): qkvbf @0 (6.3MB, alive through flash); hh @8MB (9.4MB, MoE)
    char* reg2 = A8(20 * 1024 * 1024);
    f16* qkvbf = (f16*)reg2;
    f16* hh    = (f16*)(reg2 + 8 * 1024 * 1024);

    f16* WtEnc = (f16*)A8((size_t)256 * 1152 * 2);
    f16* Wqkvt = (f16*)A8((size_t)768 * 256 * 2);
    f16* Wot   = (f16*)A8((size_t)256 * 256 * 2);
    f16* W1t   = (f16*)A8((size_t)4 * 1024 * 256 * 2);
    f16* W2t   = (f16*)A8((size_t)4 * 256 * 1024 * 2);
    f16* Wg1t  = (f16*)A8((size_t)256 * 256 * 2);
    f16* Wg2t  = (f16*)A8((size_t)4000 * 256 * 2);
    f16* Wf1t  = (f16*)A8((size_t)64 * 256 * 2);
    f16* Vt    = (f16*)A8((size_t)256 * NTOK * 2);
    float2* mlpart = (float2*)A8((size_t)16 * NTOK * 8);
    float* benc    = (float*)A8(256 * 4);
    float* biasqkv = (float*)A8(768 * 4);
    float* z    = (float*)A8((size_t)NTOK * DMODEL * 4);
    float* z2   = (float*)A8((size_t)NTOK * DMODEL * 4);
    float* attn = (float*)A8((size_t)NTOK * DMODEL * 4);
    float* tbuf = (float*)A8((size_t)NTOK * DMODEL * 4);
    f16* zbf    = (f16*)A8((size_t)NTOK * DMODEL * 2);
    f16* z2bf   = (f16*)A8((size_t)NTOK * DMODEL * 2);
    f16* z3bf   = (f16*)A8((size_t)NTOK * DMODEL * 2);
    f16* ctxbf  = (f16*)A8((size_t)NTOK * DMODEL * 2);
    f16* dbufbf = (f16*)A8((size_t)NTOK * DMODEL * 2);
    f16* fbf    = (f16*)A8((size_t)NTOK * 64 * 2);
    int* eidb   = (int*)A8(NTOK * 4);
    float* gval = (float*)A8(NTOK * 4);
    int* gidx   = (int*)A8(4608 * 4);
    int* temap  = (int*)A8(64 * 4);

    dim3 blk(256);

    // ---- weight prep (flat tile list; all dims multiples of 32) ----
    TDs td;
    int nd = 0, pre = 0;
    auto addT = [&](const float* s, f16* d, int R, int C, int ldo) {
        td.t[nd] = TD{s, d, R, C, ldo};
        td.pre[nd] = pre;
        pre += (R >> 5) * (C >> 5);
        nd++;
    };
    addT(W_img, WtEnc, 1024, 256, 1152);
    addT(W_pos, WtEnc + 1024, 128, 256, 1152);
    addT(Wq, Wqkvt, 256, 256, 256);
    addT(Wk, Wqkvt + 256 * 256, 256, 256, 256);
    addT(Wv, Wqkvt + 512 * 256, 256, 256, 256);
    addT(Wo, Wot, 256, 256, 256);
    for (int e = 0; e < 4; e++) addT(W1e + (size_t)e * 262144, W1t + (size_t)e * 262144, 256, 1024, 256);
    for (int e = 0; e < 4; e++) addT(W2e + (size_t)e * 262144, W2t + (size_t)e * 262144, 1024, 256, 1024);
    addT(Wg1, Wg1t, 256, 256, 256);
    addT(Wg2, Wg2t, 256, 4000, 256);
    addT(Wf1, Wf1t, 256, 64, 256);
    td.pre[nd] = pre;
    tconv_k<<<pre, blk, 0, stream>>>(td);
    addbias_k<<<1, blk, 0, stream>>>(b_img, b_pos, benc);
    hipMemcpyAsync(biasqkv, bq, 256 * 4, hipMemcpyDeviceToDevice, stream);
    hipMemcpyAsync(biasqkv + 256, bk, 256 * 4, hipMemcpyDeviceToDevice, stream);
    hipMemcpyAsync(biasqkv + 512, bv, 256 * 4, hipMemcpyDeviceToDevice, stream);

    // ---- encoder ----
    cvt_vis_k<<<NTOK, blk, 0, stream>>>(vis, Abig);
    fourier_k<<<NTOK, 64, 0, stream>>>(pos, Bf, Abig);
    bgemm_k<1, EPI_DUAL, 0><<<dim3(32, 8, 1), blk, 0, stream>>>(
        Abig, 1152, WtEnc, 1152, benc, z, zbf, 256, 256, 1152,
        0, 0, nullptr, nullptr, nullptr, nullptr, nullptr, nullptr);

    // ---- fused QKV ----
    bgemm_k<2, EPI_F16, 0><<<dim3(32, 12, 1), blk, 0, stream>>>(
        zbf, 256, Wqkvt, 256, biasqkv, nullptr, qkvbf, 768, 768, 256,
        0, 0, nullptr, nullptr, nullptr, nullptr, nullptr, nullptr);
    tconvh_k<<<dim3(128, 8, 1), blk, 0, stream>>>(qkvbf + 512, 768, Vt, 4096);

    // ---- flash attention (split-KV x4) + combine ----
    flash_k<<<dim3(64, 4, 4), blk, 0, stream>>>(qkvbf, Vt, Opart, mlpart);
    fcomb_k<<<1024, blk, 0, stream>>>(Opart, mlpart, ctxbf);
    bgemm_k<1, EPI_F32, 0><<<dim3(32, 8, 1), blk, 0, stream>>>(
        ctxbf, 256, Wot, 256, bo, attn, nullptr, 256, 256, 256,
        0, 0, nullptr, nullptr, nullptr, nullptr, nullptr, nullptr);
    ln_k<<<NTOK, blk, 0, stream>>>(z, attn, ln1g, ln1b, z2, z2bf, 0);

    // ---- MoE: top-1 gather -> grouped GEMMs -> scatter ----
    router_k<<<NTOK, 64, 0, stream>>>(z2, grad, Wr, br, eidb, gval);
    compact_k<<<1, blk, 0, stream>>>(eidb, gidx, temap);
    bgemm_k<4, EPI_GELU_F16, 1><<<dim3(36, 8, 1), blk, 0, stream>>>(
        z2bf, 256, W1t, 256, b1e, nullptr, hh, 1024, 1024, 256,
        262144, 1024, gidx, temap, nullptr, nullptr, nullptr, nullptr);
    bgemm_k<2, EPI_MOESC, 2><<<dim3(36, 4, 1), blk, 0, stream>>>(
        hh, 1024, W2t, 1024, b2e, nullptr, z3bf, 256, 256, 1024,
        262144, 256, gidx, temap, z2, gval, nullptr, nullptr);

    // ---- gene decoder ----
    bgemm_k<1, EPI_F32, 0><<<dim3(32, 8, 1), blk, 0, stream>>>(
        z3bf, 256, Wg1t, 256, bg1, tbuf, nullptr, 256, 256, 256,
        0, 0, nullptr, nullptr, nullptr, nullptr, nullptr, nullptr);
    ln_k<<<NTOK, blk, 0, stream>>>(tbuf, nullptr, lngg, lngb, nullptr, dbufbf, 1);
    bgemm_k<4, EPI_GENE, 0><<<dim3(32, 32, 1), blk, 0, stream>>>(
        dbufbf, 256, Wg2t, 256, bg2, nullptr, nullptr, 4000, 4000, 256,
        0, 0, nullptr, nullptr, nullptr, nullptr, outMu, outTh);

    // ---- functional head ----
    bgemm_k<1, EPI_GELU_F16, 0><<<dim3(32, 2, 1), blk, 0, stream>>>(
        z3bf, 256, Wf1t, 256, bf1, nullptr, fbf, 64, 64, 256,
        0, 0, nullptr, nullptr, nullptr, nullptr, nullptr, nullptr);
    ghead_k<<<NTOK / 256, blk, 0, stream>>>(fbf, Wf2, bf2, outG);
}